// Round 1
// baseline (6002.114 us; speedup 1.0000x reference)
//
#include <hip/hip_runtime.h>
#include <hip/hip_bf16.h>

namespace {

constexpr int HN  = 128;
constexpr int N0  = 80000, N1 = 60000, N2 = 45000;
constexpr int CIN = 64;
constexpr int E0  = 1280000, E1 = 360000, E2 = 315000;

__global__ void hist_kernel(const int* __restrict__ idx, int n, float* __restrict__ cnt) {
    int i = blockIdx.x * blockDim.x + threadIdx.x;
    if (i < n) unsafeAtomicAdd(&cnt[idx[i]], 1.0f);
}

__global__ void dinv_kernel(float* __restrict__ d, int n) {
    int i = blockIdx.x * blockDim.x + threadIdx.x;
    if (i < n) d[i] = rsqrtf(d[i] + 2.0f);
}

__global__ void invperm_kernel(const int* __restrict__ perm, int n, int* __restrict__ inv) {
    int i = blockIdx.x * blockDim.x + threadIdx.x;
    if (i < n) inv[perm[i]] = i;
}

// dst[i,:] = src_row(i) @ W[0:K,:]  (+ extraVal[i]*Wex[:] ) (+ bias)
// MODE 0: src_row(i) = src[i]
// MODE 1: r = rowidx[i]; src_row = (r >= 0) ? src[r] : 0
template<int K, int MODE, bool EXTRA, bool BIAS>
__global__ __launch_bounds__(256) void gemm_kernel(
    const float* __restrict__ src,
    const int*   __restrict__ rowidx,
    const float* __restrict__ extraVal, int extraLimit,
    const float* __restrict__ Wex,
    const float* __restrict__ W,
    const float* __restrict__ bias,
    float* __restrict__ dst, int M)
{
    __shared__ float Wl[K * 64];   // [K][64] col-slice of W
    __shared__ float hl[64 * K];   // [64][K] row tile, float4-group XOR swizzled

    const int rowbase = blockIdx.x * 64;
    const int colbase = blockIdx.y * 64;
    const int tid = threadIdx.x;

    // stage W[:, colbase:colbase+64]
    for (int t = tid; t < K * 16; t += 256) {
        int k = t >> 4, c4 = t & 15;
        float4 w = *reinterpret_cast<const float4*>(&W[k * HN + colbase + c4 * 4]);
        *reinterpret_cast<float4*>(&Wl[k * 64 + c4 * 4]) = w;
    }
    // stage 64 rows of h (zero-fill OOB / -1 rows), swizzle float4 groups
    for (int t = tid; t < 16 * K; t += 256) {
        int row = t / (K / 4), g = t % (K / 4);
        int grow = rowbase + row;
        float4 v = make_float4(0.f, 0.f, 0.f, 0.f);
        if (grow < M) {
            int r = (MODE == 0) ? grow : rowidx[grow];
            if (r >= 0) v = *reinterpret_cast<const float4*>(&src[(size_t)r * K + g * 4]);
        }
        int gs = g ^ ((row >> 2) & 7);
        *reinterpret_cast<float4*>(&hl[row * K + gs * 4]) = v;
    }
    __syncthreads();

    const int cg = tid & 15;   // 4-col group -> cols colbase + cg*4 .. +3
    const int rs = tid >> 4;   // 4-row slot  -> rows rowbase + rs*4 .. +3

    float acc[4][4];
    #pragma unroll
    for (int r = 0; r < 4; ++r)
        #pragma unroll
        for (int j = 0; j < 4; ++j) acc[r][j] = 0.f;

    #pragma unroll 4
    for (int g = 0; g < K / 4; ++g) {
        float4 wv[4];
        #pragma unroll
        for (int kk = 0; kk < 4; ++kk)
            wv[kk] = *reinterpret_cast<const float4*>(&Wl[(g * 4 + kk) * 64 + cg * 4]);
        #pragma unroll
        for (int r = 0; r < 4; ++r) {
            int row = rs * 4 + r;
            int gs = g ^ ((row >> 2) & 7);
            float4 hv = *reinterpret_cast<const float4*>(&hl[row * K + gs * 4]);
            acc[r][0] += hv.x * wv[0].x + hv.y * wv[1].x + hv.z * wv[2].x + hv.w * wv[3].x;
            acc[r][1] += hv.x * wv[0].y + hv.y * wv[1].y + hv.z * wv[2].y + hv.w * wv[3].y;
            acc[r][2] += hv.x * wv[0].z + hv.y * wv[1].z + hv.z * wv[2].z + hv.w * wv[3].z;
            acc[r][3] += hv.x * wv[0].w + hv.y * wv[1].w + hv.z * wv[2].w + hv.w * wv[3].w;
        }
    }

    #pragma unroll
    for (int r = 0; r < 4; ++r) {
        int i = rowbase + rs * 4 + r;
        if (i >= M) continue;
        if (EXTRA) {
            float ev = (i < extraLimit) ? extraVal[i] : 0.f;
            #pragma unroll
            for (int j = 0; j < 4; ++j) acc[r][j] += ev * Wex[colbase + cg * 4 + j];
        }
        if (BIAS) {
            #pragma unroll
            for (int j = 0; j < 4; ++j) acc[r][j] += bias[colbase + cg * 4 + j];
        }
        float4 o = make_float4(acc[r][0], acc[r][1], acc[r][2], acc[r][3]);
        *reinterpret_cast<float4*>(&dst[(size_t)i * HN + colbase + cg * 4]) = o;
    }
}

// out[col,:] += dinv[row]*dinv[col] * tmp[row,:]   (32 lanes per edge, float4 each)
__global__ __launch_bounds__(256) void scatter_kernel(
    const int* __restrict__ rows, const int* __restrict__ cols, int E,
    const float* __restrict__ tmp, const float* __restrict__ dinv,
    float* __restrict__ out)
{
    int gid = blockIdx.x * blockDim.x + threadIdx.x;
    int e = gid >> 5, lane = gid & 31;
    if (e >= E) return;
    int r = rows[e], c = cols[e];
    float norm = dinv[r] * dinv[c];
    float4 v = reinterpret_cast<const float4*>(tmp + (size_t)r * HN)[lane];
    float* o = out + (size_t)c * HN + lane * 4;
    unsafeAtomicAdd(o + 0, norm * v.x);
    unsafeAtomicAdd(o + 1, norm * v.y);
    unsafeAtomicAdd(o + 2, norm * v.z);
    unsafeAtomicAdd(o + 3, norm * v.w);
}

// out = relu(out + 2*dinv[i]^2 * tmp + bias)
template<bool RELU>
__global__ __launch_bounds__(256) void epilogue_kernel(
    float* __restrict__ out, const float* __restrict__ tmp,
    const float* __restrict__ dinv, const float* __restrict__ bias, int N)
{
    int gid = blockIdx.x * blockDim.x + threadIdx.x;
    if (gid >= N * 32) return;
    int i = gid >> 5, c4 = gid & 31;
    float d = dinv[i];
    float s = 2.f * d * d;
    float4 o = reinterpret_cast<float4*>(out + (size_t)i * HN)[c4];
    float4 t = reinterpret_cast<const float4*>(tmp + (size_t)i * HN)[c4];
    float4 b = reinterpret_cast<const float4*>(bias)[c4];
    o.x += s * t.x + b.x;
    o.y += s * t.y + b.y;
    o.z += s * t.z + b.z;
    o.w += s * t.w + b.w;
    if (RELU) {
        o.x = fmaxf(o.x, 0.f); o.y = fmaxf(o.y, 0.f);
        o.z = fmaxf(o.z, 0.f); o.w = fmaxf(o.w, 0.f);
    }
    reinterpret_cast<float4*>(out + (size_t)i * HN)[c4] = o;
}

inline int cdiv(int a, int b) { return (a + b - 1) / b; }

} // namespace

extern "C" void kernel_launch(void* const* d_in, const int* in_sizes, int n_in,
                              void* d_out, int out_size, void* d_ws, size_t ws_size,
                              hipStream_t stream)
{
    const float* x       = (const float*)d_in[0];
    const float* W_down0 = (const float*)d_in[2];
    const float* b_down0 = (const float*)d_in[3];
    const float* W_down1 = (const float*)d_in[4];
    const float* b_down1 = (const float*)d_in[5];
    const float* W_up0   = (const float*)d_in[6];
    const float* b_up0   = (const float*)d_in[7];
    const float* W_up1   = (const float*)d_in[8];
    const float* b_up1   = (const float*)d_in[9];
    const float* W_lin   = (const float*)d_in[10];
    const float* b_lin   = (const float*)d_in[11];
    const int*   ei0     = (const int*)d_in[12];
    const int*   ei1     = (const int*)d_in[13];
    const int*   ei2     = (const int*)d_in[14];
    const int*   perm1   = (const int*)d_in[15];
    const int*   perm2   = (const int*)d_in[16];

    float* out = (float*)d_out;               // doubles as ping-pong buffer B
    char*  ws  = (char*)d_ws;
    float* A     = (float*)ws;                            // N0*128 f32
    float* dinv0 = (float*)(ws + (size_t)N0 * HN * 4);    // N0
    float* dinv1 = dinv0 + N0;                            // N1
    float* cntE  = dinv1 + N1;                            // N2
    int*   inv1  = (int*)(cntE + N2);                     // N0
    int*   inv2  = inv1 + N0;                             // N1

    // ---- setup: degrees, inverse perms ----
    hipMemsetAsync(dinv0, 0, (size_t)N0 * 4, stream);
    hipMemsetAsync(dinv1, 0, (size_t)N1 * 4, stream);
    hipMemsetAsync(cntE,  0, (size_t)N2 * 4, stream);
    hipMemsetAsync(inv1, 0xFF, (size_t)N0 * 4, stream);
    hipMemsetAsync(inv2, 0xFF, (size_t)N1 * 4, stream);

    hist_kernel<<<cdiv(E0, 256), 256, 0, stream>>>(ei0 + E0, E0, dinv0);
    hist_kernel<<<cdiv(E1, 256), 256, 0, stream>>>(ei1 + E1, E1, dinv1);
    hist_kernel<<<cdiv(2 * E2, 256), 256, 0, stream>>>(ei2, 2 * E2, cntE);
    dinv_kernel<<<cdiv(N0, 256), 256, 0, stream>>>(dinv0, N0);
    dinv_kernel<<<cdiv(N1, 256), 256, 0, stream>>>(dinv1, N1);
    invperm_kernel<<<cdiv(N1, 256), 256, 0, stream>>>(perm1, N1, inv1);
    invperm_kernel<<<cdiv(N2, 256), 256, 0, stream>>>(perm2, N2, inv2);

    // ---- L0: h0 = relu(gcn(x, ei0, W_down0, b_down0)) -> out ----
    gemm_kernel<CIN, 0, false, false><<<dim3(cdiv(N0, 64), 2), 256, 0, stream>>>(
        x, nullptr, nullptr, 0, nullptr, W_down0, nullptr, A, N0);
    hipMemsetAsync(out, 0, (size_t)N0 * HN * 4, stream);
    scatter_kernel<<<cdiv(E0 * 32, 256), 256, 0, stream>>>(ei0, ei0 + E0, E0, A, dinv0, out);
    epilogue_kernel<true><<<cdiv(N0 * 32, 256), 256, 0, stream>>>(out, A, dinv0, b_down0, N0);

    // ---- L1: h1 = relu(gcn(h0[perm1], ei1, W_down1, b_down1)) -> out ----
    gemm_kernel<HN, 1, false, false><<<dim3(cdiv(N1, 64), 2), 256, 0, stream>>>(
        out, perm1, nullptr, 0, nullptr, W_down1, nullptr, A, N1);
    hipMemsetAsync(out, 0, (size_t)N1 * HN * 4, stream);
    scatter_kernel<<<cdiv(E1 * 32, 256), 256, 0, stream>>>(ei1, ei1 + E1, E1, A, dinv1, out);
    epilogue_kernel<true><<<cdiv(N1 * 32, 256), 256, 0, stream>>>(out, A, dinv1, b_down1, N1);

    // ---- L2: g1 = relu(gcn([unpool2(h1), degE], ei1, W_up0, b_up0)) -> out ----
    gemm_kernel<HN, 1, true, false><<<dim3(cdiv(N1, 64), 2), 256, 0, stream>>>(
        out, inv2, cntE, N2, W_up0 + 128 * HN, W_up0, nullptr, A, N1);
    hipMemsetAsync(out, 0, (size_t)N1 * HN * 4, stream);
    scatter_kernel<<<cdiv(E1 * 32, 256), 256, 0, stream>>>(ei1, ei1 + E1, E1, A, dinv1, out);
    epilogue_kernel<true><<<cdiv(N1 * 32, 256), 256, 0, stream>>>(out, A, dinv1, b_up0, N1);

    // ---- L3: g0 = relu(gcn([unpool1(g1), degE], ei0, W_up1, b_up1)) -> out ----
    gemm_kernel<HN, 1, true, false><<<dim3(cdiv(N0, 64), 2), 256, 0, stream>>>(
        out, inv1, cntE, N2, W_up1 + 128 * HN, W_up1, nullptr, A, N0);
    hipMemsetAsync(out, 0, (size_t)N0 * HN * 4, stream);
    scatter_kernel<<<cdiv(E0 * 32, 256), 256, 0, stream>>>(ei0, ei0 + E0, E0, A, dinv0, out);
    epilogue_kernel<true><<<cdiv(N0 * 32, 256), 256, 0, stream>>>(out, A, dinv0, b_up1, N0);

    // ---- final: d_out = g0 @ W_lin + b_lin ----
    gemm_kernel<HN, 0, false, true><<<dim3(cdiv(N0, 64), 2), 256, 0, stream>>>(
        out, nullptr, nullptr, 0, nullptr, W_lin, b_lin, A, N0);
    hipMemcpyAsync(d_out, A, (size_t)N0 * HN * 4, hipMemcpyDeviceToDevice, stream);
}

// Round 2
// 796.629 us; speedup vs baseline: 7.5344x; 7.5344x over previous
//
#include <hip/hip_runtime.h>
#include <hip/hip_bf16.h>

namespace {

constexpr int HN  = 128;
constexpr int N0  = 80000, N1 = 60000, N2 = 45000;
constexpr int CIN = 64;
constexpr int E0  = 1280000, E1 = 360000, E2 = 315000;

__global__ void hist_int_kernel(const int* __restrict__ idx, int n, int* __restrict__ cnt) {
    int i = blockIdx.x * blockDim.x + threadIdx.x;
    if (i < n) atomicAdd(&cnt[idx[i]], 1);
}

__global__ void hist_f_kernel(const int* __restrict__ idx, int n, float* __restrict__ cnt) {
    int i = blockIdx.x * blockDim.x + threadIdx.x;
    if (i < n) unsafeAtomicAdd(&cnt[idx[i]], 1.0f);
}

__global__ void dinv_kernel(const int* __restrict__ cnt, float* __restrict__ d, int n) {
    int i = blockIdx.x * blockDim.x + threadIdx.x;
    if (i < n) d[i] = rsqrtf((float)cnt[i] + 2.0f);
}

__global__ void invperm_kernel(const int* __restrict__ perm, int n, int* __restrict__ inv) {
    int i = blockIdx.x * blockDim.x + threadIdx.x;
    if (i < n) inv[perm[i]] = i;
}

// Two independent exclusive scans (blockIdx.x selects which array). 1024 threads.
__global__ __launch_bounds__(1024) void scan2_kernel(
    const int* __restrict__ degA, int nA, int* __restrict__ offA,
    const int* __restrict__ degB, int nB, int* __restrict__ offB)
{
    const int* deg = blockIdx.x == 0 ? degA : degB;
    int n          = blockIdx.x == 0 ? nA   : nB;
    int* off       = blockIdx.x == 0 ? offA : offB;

    __shared__ int wsum[16];
    int tid = threadIdx.x;
    int lane = tid & 63, w = tid >> 6;
    int total = 0;
    for (int base = 0; base < n; base += 1024) {
        int v = (base + tid < n) ? deg[base + tid] : 0;
        int s = v;
        #pragma unroll
        for (int d = 1; d < 64; d <<= 1) {
            int t = __shfl_up(s, d, 64);
            if (lane >= d) s += t;
        }
        __syncthreads();                 // protect wsum from previous-iter reads
        if (lane == 63) wsum[w] = s;
        __syncthreads();
        if (w == 0 && lane < 16) {
            int ws = wsum[lane];
            #pragma unroll
            for (int d = 1; d < 16; d <<= 1) {
                int t = __shfl_up(ws, d, 64);
                if (lane >= d) ws += t;
            }
            wsum[lane] = ws;
        }
        __syncthreads();
        int wbase = (w > 0) ? wsum[w - 1] : 0;
        if (base + tid < n) off[base + tid] = total + wbase + s - v;
        total += wsum[15];
    }
    if (tid == 0) off[n] = total;
}

__global__ void fill_kernel(const int* __restrict__ rows, const int* __restrict__ cols, int E,
                            const int* __restrict__ off, int* __restrict__ cur,
                            int* __restrict__ csr)
{
    int e = blockIdx.x * blockDim.x + threadIdx.x;
    if (e >= E) return;
    int c = cols[e];
    int p = atomicAdd(&cur[c], 1);
    csr[off[c] + p] = rows[e];
}

// dst[i,:] = src_row(i) @ W[0:K,:] (+extraVal[i]*Wex) (+bias) (*dinv[i] if SCALE)
// MODE 0: src_row(i)=src[i]; MODE 1: r=rowidx[i], r>=0?src[r]:0;
// MODE 2: src_row(i)= rowidx[i]>=0 ? src[i] : 0   (masked self)
template<int K, int MODE, bool EXTRA, bool BIAS, bool SCALE>
__global__ __launch_bounds__(256) void gemm_kernel(
    const float* __restrict__ src,
    const int*   __restrict__ rowidx,
    const float* __restrict__ extraVal, int extraLimit,
    const float* __restrict__ Wex,
    const float* __restrict__ W,
    const float* __restrict__ bias,
    const float* __restrict__ dinv,
    float* __restrict__ dst, int M)
{
    __shared__ float Wl[K * 64];
    __shared__ float hl[64 * K];

    const int rowbase = blockIdx.x * 64;
    const int colbase = blockIdx.y * 64;
    const int tid = threadIdx.x;

    for (int t = tid; t < K * 16; t += 256) {
        int k = t >> 4, c4 = t & 15;
        float4 wv = *reinterpret_cast<const float4*>(&W[k * HN + colbase + c4 * 4]);
        *reinterpret_cast<float4*>(&Wl[k * 64 + c4 * 4]) = wv;
    }
    for (int t = tid; t < 16 * K; t += 256) {
        int row = t / (K / 4), g = t % (K / 4);
        int grow = rowbase + row;
        float4 v = make_float4(0.f, 0.f, 0.f, 0.f);
        if (grow < M) {
            int r;
            if (MODE == 0) r = grow;
            else if (MODE == 1) r = rowidx[grow];
            else r = (rowidx[grow] >= 0) ? grow : -1;
            if (r >= 0) v = *reinterpret_cast<const float4*>(&src[(size_t)r * K + g * 4]);
        }
        int gs = g ^ ((row >> 2) & 7);
        *reinterpret_cast<float4*>(&hl[row * K + gs * 4]) = v;
    }
    __syncthreads();

    const int cg = tid & 15;
    const int rs = tid >> 4;

    float acc[4][4];
    #pragma unroll
    for (int r = 0; r < 4; ++r)
        #pragma unroll
        for (int j = 0; j < 4; ++j) acc[r][j] = 0.f;

    #pragma unroll 4
    for (int g = 0; g < K / 4; ++g) {
        float4 wv[4];
        #pragma unroll
        for (int kk = 0; kk < 4; ++kk)
            wv[kk] = *reinterpret_cast<const float4*>(&Wl[(g * 4 + kk) * 64 + cg * 4]);
        #pragma unroll
        for (int r = 0; r < 4; ++r) {
            int row = rs * 4 + r;
            int gs = g ^ ((row >> 2) & 7);
            float4 hv = *reinterpret_cast<const float4*>(&hl[row * K + gs * 4]);
            acc[r][0] += hv.x * wv[0].x + hv.y * wv[1].x + hv.z * wv[2].x + hv.w * wv[3].x;
            acc[r][1] += hv.x * wv[0].y + hv.y * wv[1].y + hv.z * wv[2].y + hv.w * wv[3].y;
            acc[r][2] += hv.x * wv[0].z + hv.y * wv[1].z + hv.z * wv[2].z + hv.w * wv[3].z;
            acc[r][3] += hv.x * wv[0].w + hv.y * wv[1].w + hv.z * wv[2].w + hv.w * wv[3].w;
        }
    }

    #pragma unroll
    for (int r = 0; r < 4; ++r) {
        int i = rowbase + rs * 4 + r;
        if (i >= M) continue;
        if (EXTRA) {
            float ev = (i < extraLimit) ? extraVal[i] : 0.f;
            #pragma unroll
            for (int j = 0; j < 4; ++j) acc[r][j] += ev * Wex[colbase + cg * 4 + j];
        }
        if (BIAS) {
            #pragma unroll
            for (int j = 0; j < 4; ++j) acc[r][j] += bias[colbase + cg * 4 + j];
        }
        if (SCALE) {
            float d = dinv[i];
            #pragma unroll
            for (int j = 0; j < 4; ++j) acc[r][j] *= d;
        }
        float4 o = make_float4(acc[r][0], acc[r][1], acc[r][2], acc[r][3]);
        *reinterpret_cast<float4*>(&dst[(size_t)i * HN + colbase + cg * 4]) = o;
    }
}

// out[i,:] = relu( dinv[i] * ( sum_{e in in(i)} tmp[csr[e],:] + 2*tmp[i,:] ) + bias )
// tmp is pre-scaled by dinv (A = dinv[r] * (h @ W)).
template<bool RELU>
__global__ __launch_bounds__(256) void gather_kernel(
    const int* __restrict__ off, const int* __restrict__ csr,
    const float* __restrict__ tmp, const float* __restrict__ dinv,
    const float* __restrict__ bias,
    float* __restrict__ out, int N)
{
    int gid = blockIdx.x * blockDim.x + threadIdx.x;
    int i = gid >> 5, lane = gid & 31;
    if (i >= N) return;
    int e = off[i], e1 = off[i + 1];
    float4 acc = make_float4(0.f, 0.f, 0.f, 0.f);
    for (; e + 4 <= e1; e += 4) {
        int s0 = csr[e], s1 = csr[e + 1], s2 = csr[e + 2], s3 = csr[e + 3];
        float4 v0 = reinterpret_cast<const float4*>(tmp + (size_t)s0 * HN)[lane];
        float4 v1 = reinterpret_cast<const float4*>(tmp + (size_t)s1 * HN)[lane];
        float4 v2 = reinterpret_cast<const float4*>(tmp + (size_t)s2 * HN)[lane];
        float4 v3 = reinterpret_cast<const float4*>(tmp + (size_t)s3 * HN)[lane];
        acc.x += v0.x + v1.x + v2.x + v3.x;
        acc.y += v0.y + v1.y + v2.y + v3.y;
        acc.z += v0.z + v1.z + v2.z + v3.z;
        acc.w += v0.w + v1.w + v2.w + v3.w;
    }
    for (; e < e1; ++e) {
        int s = csr[e];
        float4 v = reinterpret_cast<const float4*>(tmp + (size_t)s * HN)[lane];
        acc.x += v.x; acc.y += v.y; acc.z += v.z; acc.w += v.w;
    }
    float d = dinv[i];
    float4 t = reinterpret_cast<const float4*>(tmp + (size_t)i * HN)[lane];
    float4 b = reinterpret_cast<const float4*>(bias)[lane];
    float4 o;
    o.x = d * (acc.x + 2.f * t.x) + b.x;
    o.y = d * (acc.y + 2.f * t.y) + b.y;
    o.z = d * (acc.z + 2.f * t.z) + b.z;
    o.w = d * (acc.w + 2.f * t.w) + b.w;
    if (RELU) {
        o.x = fmaxf(o.x, 0.f); o.y = fmaxf(o.y, 0.f);
        o.z = fmaxf(o.z, 0.f); o.w = fmaxf(o.w, 0.f);
    }
    reinterpret_cast<float4*>(out + (size_t)i * HN)[lane] = o;
}

inline int cdiv(int a, int b) { return (a + b - 1) / b; }

} // namespace

extern "C" void kernel_launch(void* const* d_in, const int* in_sizes, int n_in,
                              void* d_out, int out_size, void* d_ws, size_t ws_size,
                              hipStream_t stream)
{
    const float* x       = (const float*)d_in[0];
    const float* W_down0 = (const float*)d_in[2];
    const float* b_down0 = (const float*)d_in[3];
    const float* W_down1 = (const float*)d_in[4];
    const float* b_down1 = (const float*)d_in[5];
    const float* W_up0   = (const float*)d_in[6];
    const float* b_up0   = (const float*)d_in[7];
    const float* W_up1   = (const float*)d_in[8];
    const float* b_up1   = (const float*)d_in[9];
    const float* W_lin   = (const float*)d_in[10];
    const float* b_lin   = (const float*)d_in[11];
    const int*   ei0     = (const int*)d_in[12];
    const int*   ei1     = (const int*)d_in[13];
    const int*   ei2     = (const int*)d_in[14];
    const int*   perm1   = (const int*)d_in[15];
    const int*   perm2   = (const int*)d_in[16];

    float* out = (float*)d_out;                 // ping-pong buffer B [N0,128]
    char*  ws  = (char*)d_ws;
    size_t o = 0;
    auto carve = [&](size_t bytes) { void* p = ws + o; o += (bytes + 15) & ~size_t(15); return p; };

    float* A     = (float*)carve((size_t)N0 * HN * 4);
    // contiguous zero block
    size_t zero_off = o;
    int*   cnt0  = (int*)  carve((size_t)N0 * 4);
    int*   cnt1  = (int*)  carve((size_t)N1 * 4);
    int*   cur0  = (int*)  carve((size_t)N0 * 4);
    int*   cur1  = (int*)  carve((size_t)N1 * 4);
    float* cntE  = (float*)carve((size_t)N2 * 4);
    size_t zero_bytes = o - zero_off;
    // contiguous 0xFF block
    size_t ff_off = o;
    int*   inv1  = (int*)  carve((size_t)N0 * 4);
    int*   inv2  = (int*)  carve((size_t)N1 * 4);
    size_t ff_bytes = o - ff_off;
    float* dinv0 = (float*)carve((size_t)N0 * 4);
    float* dinv1 = (float*)carve((size_t)N1 * 4);
    int*   off0  = (int*)  carve((size_t)(N0 + 1) * 4);
    int*   off1  = (int*)  carve((size_t)(N1 + 1) * 4);
    int*   csr0  = (int*)  carve((size_t)E0 * 4);
    int*   csr1  = (int*)  carve((size_t)E1 * 4);

    hipMemsetAsync(ws + zero_off, 0,    zero_bytes, stream);
    hipMemsetAsync(ws + ff_off,   0xFF, ff_bytes,   stream);

    // ---- degrees, inverse perms, CSR ----
    hist_int_kernel<<<cdiv(E0, 256), 256, 0, stream>>>(ei0 + E0, E0, cnt0);
    hist_int_kernel<<<cdiv(E1, 256), 256, 0, stream>>>(ei1 + E1, E1, cnt1);
    hist_f_kernel<<<cdiv(2 * E2, 256), 256, 0, stream>>>(ei2, 2 * E2, cntE);
    dinv_kernel<<<cdiv(N0, 256), 256, 0, stream>>>(cnt0, dinv0, N0);
    dinv_kernel<<<cdiv(N1, 256), 256, 0, stream>>>(cnt1, dinv1, N1);
    invperm_kernel<<<cdiv(N1, 256), 256, 0, stream>>>(perm1, N1, inv1);
    invperm_kernel<<<cdiv(N2, 256), 256, 0, stream>>>(perm2, N2, inv2);
    scan2_kernel<<<2, 1024, 0, stream>>>(cnt0, N0, off0, cnt1, N1, off1);
    fill_kernel<<<cdiv(E0, 256), 256, 0, stream>>>(ei0, ei0 + E0, E0, off0, cur0, csr0);
    fill_kernel<<<cdiv(E1, 256), 256, 0, stream>>>(ei1, ei1 + E1, E1, off1, cur1, csr1);

    // ---- L0: h0 = relu(gcn(x, ei0, W_down0, b_down0)) -> out ----
    gemm_kernel<CIN, 0, false, false, true><<<dim3(cdiv(N0, 64), 2), 256, 0, stream>>>(
        x, nullptr, nullptr, 0, nullptr, W_down0, nullptr, dinv0, A, N0);
    gather_kernel<true><<<cdiv(N0 * 32, 256), 256, 0, stream>>>(off0, csr0, A, dinv0, b_down0, out, N0);

    // ---- L1: h1 = relu(gcn(h0[perm1], ei1, W_down1, b_down1)) -> out ----
    gemm_kernel<HN, 1, false, false, true><<<dim3(cdiv(N1, 64), 2), 256, 0, stream>>>(
        out, perm1, nullptr, 0, nullptr, W_down1, nullptr, dinv1, A, N1);
    gather_kernel<true><<<cdiv(N1 * 32, 256), 256, 0, stream>>>(off1, csr1, A, dinv1, b_down1, out, N1);

    // ---- L2: g1 = relu(gcn([unpool2(h1), degE], ei1, W_up0, b_up0)) -> out ----
    gemm_kernel<HN, 2, true, false, true><<<dim3(cdiv(N1, 64), 2), 256, 0, stream>>>(
        out, inv2, cntE, N2, W_up0 + 128 * HN, W_up0, nullptr, dinv1, A, N1);
    gather_kernel<true><<<cdiv(N1 * 32, 256), 256, 0, stream>>>(off1, csr1, A, dinv1, b_up0, out, N1);

    // ---- L3: g0 = relu(gcn([unpool1(g1), degE], ei0, W_up1, b_up1)) -> out ----
    gemm_kernel<HN, 1, true, false, true><<<dim3(cdiv(N0, 64), 2), 256, 0, stream>>>(
        out, inv1, cntE, N2, W_up1 + 128 * HN, W_up1, nullptr, dinv0, A, N0);
    gather_kernel<true><<<cdiv(N0 * 32, 256), 256, 0, stream>>>(off0, csr0, A, dinv0, b_up1, out, N0);

    // ---- final: d_out = g0 @ W_lin + b_lin ----
    gemm_kernel<HN, 0, false, true, false><<<dim3(cdiv(N0, 64), 2), 256, 0, stream>>>(
        out, nullptr, nullptr, 0, nullptr, W_lin, b_lin, nullptr, A, N0);
    hipMemcpyAsync(d_out, A, (size_t)N0 * HN * 4, hipMemcpyDeviceToDevice, stream);
}

// Round 3
// 510.328 us; speedup vs baseline: 11.7613x; 1.5610x over previous
//
#include <hip/hip_runtime.h>
#include <hip/hip_bf16.h>

namespace {

constexpr int HN  = 128;
constexpr int N0  = 80000, N1 = 60000, N2 = 45000;
constexpr int CIN = 64;
constexpr int E0  = 1280000, E1 = 360000, E2 = 315000;

using short8 = __attribute__((ext_vector_type(8))) short;
using f32x4  = __attribute__((ext_vector_type(4))) float;

__device__ inline ushort f2bf(float f) {
    uint u = __float_as_uint(f);
    u += 0x7fffu + ((u >> 16) & 1u);
    return (ushort)(u >> 16);
}
__device__ inline float bf2f(ushort u) {
    return __uint_as_float(((uint)u) << 16);
}

__global__ void hist_int_kernel(const int* __restrict__ idx, int n, int* __restrict__ cnt) {
    int i = blockIdx.x * blockDim.x + threadIdx.x;
    if (i < n) atomicAdd(&cnt[idx[i]], 1);
}

__global__ void hist_f_kernel(const int* __restrict__ idx, int n, float* __restrict__ cnt) {
    int i = blockIdx.x * blockDim.x + threadIdx.x;
    if (i < n) unsafeAtomicAdd(&cnt[idx[i]], 1.0f);
}

__global__ void dinv_kernel(const int* __restrict__ cnt, float* __restrict__ d, int n) {
    int i = blockIdx.x * blockDim.x + threadIdx.x;
    if (i < n) d[i] = rsqrtf((float)cnt[i] + 2.0f);
}

__global__ void invperm_kernel(const int* __restrict__ perm, int n, int* __restrict__ inv) {
    int i = blockIdx.x * blockDim.x + threadIdx.x;
    if (i < n) inv[perm[i]] = i;
}

// transpose+convert the 5 weight matrices: Wt[n][k] = bf16(W[k][n])
__global__ void wprep_kernel(const float* W0, const float* W1, const float* W2,
                             const float* W3, const float* W4,
                             ushort* T0, ushort* T1, ushort* T2, ushort* T3, ushort* T4)
{
    int m = blockIdx.y;
    const float* W; ushort* T; int K;
    switch (m) {
        case 0: W = W0; T = T0; K = CIN; break;
        case 1: W = W1; T = T1; K = HN;  break;
        case 2: W = W2; T = T2; K = HN;  break;
        case 3: W = W3; T = T3; K = HN;  break;
        default: W = W4; T = T4; K = HN; break;
    }
    int idx = blockIdx.x * 256 + threadIdx.x;
    if (idx >= K * HN) return;
    int n = idx / K, k = idx - n * K;
    T[idx] = f2bf(W[k * HN + n]);
}

// Two independent exclusive scans (blockIdx.x selects which). 1024 threads.
__global__ __launch_bounds__(1024) void scan2_kernel(
    const int* __restrict__ degA, int nA, int* __restrict__ offA,
    const int* __restrict__ degB, int nB, int* __restrict__ offB)
{
    const int* deg = blockIdx.x == 0 ? degA : degB;
    int n          = blockIdx.x == 0 ? nA   : nB;
    int* off       = blockIdx.x == 0 ? offA : offB;

    __shared__ int wsum[16];
    int tid = threadIdx.x;
    int lane = tid & 63, w = tid >> 6;
    int total = 0;
    for (int base = 0; base < n; base += 1024) {
        int v = (base + tid < n) ? deg[base + tid] : 0;
        int s = v;
        #pragma unroll
        for (int d = 1; d < 64; d <<= 1) {
            int t = __shfl_up(s, d, 64);
            if (lane >= d) s += t;
        }
        __syncthreads();
        if (lane == 63) wsum[w] = s;
        __syncthreads();
        if (w == 0 && lane < 16) {
            int ws = wsum[lane];
            #pragma unroll
            for (int d = 1; d < 16; d <<= 1) {
                int t = __shfl_up(ws, d, 64);
                if (lane >= d) ws += t;
            }
            wsum[lane] = ws;
        }
        __syncthreads();
        int wbase = (w > 0) ? wsum[w - 1] : 0;
        if (base + tid < n) off[base + tid] = total + wbase + s - v;
        total += wsum[15];
    }
    if (tid == 0) off[n] = total;
}

__global__ void fill_kernel(const int* __restrict__ rows, const int* __restrict__ cols, int E,
                            const int* __restrict__ off, int* __restrict__ cur,
                            int* __restrict__ csr)
{
    int e = blockIdx.x * blockDim.x + threadIdx.x;
    if (e >= E) return;
    int c = cols[e];
    int p = atomicAdd(&cur[c], 1);
    csr[off[c] + p] = rows[e];
}

// dst[i,:] = src_row(i) @ W (+extraVal[i]*Wex) (+bias) (*dinv[i] if SCALE)
// MODE 0: row i; MODE 1: r=rowidx[i] (>=0 else zero row); MODE 2: zero unless rowidx[i]>=0.
// A-frags read directly from global; B-frags from pre-transposed Wt[n][k] bf16.
template<int K, int MODE, bool AF32, bool EXTRA, bool BIAS, bool SCALE, bool OUTF32>
__global__ __launch_bounds__(256) void mfma_gemm_kernel(
    const void* __restrict__ srcv,
    const int* __restrict__ rowidx,
    const float* __restrict__ extraVal, int extraLimit,
    const float* __restrict__ Wex,
    const ushort* __restrict__ Wt,
    const float* __restrict__ bias,
    const float* __restrict__ dinv,
    void* __restrict__ dstv, int M)
{
    constexpr int KB = K / 32;
    const int tid  = threadIdx.x;
    const int wid  = tid >> 6, lane = tid & 63;
    const int l15  = lane & 15, lhi = lane >> 4;
    const int rowbase = blockIdx.x * 128 + wid * 32;

    // ---- A fragments: lane holds row (l15), k = kb*32 + lhi*8 .. +8 ----
    short8 a[2][KB];
    #pragma unroll
    for (int mf = 0; mf < 2; ++mf) {
        int i = rowbase + mf * 16 + l15;
        int r = -1;
        if (i < M) {
            if (MODE == 0) r = i;
            else if (MODE == 1) r = rowidx[i];
            else r = (rowidx[i] >= 0) ? i : -1;
        }
        #pragma unroll
        for (int kb = 0; kb < KB; ++kb) {
            int ko = kb * 32 + lhi * 8;
            short8 v = {0, 0, 0, 0, 0, 0, 0, 0};
            if (r >= 0) {
                if (AF32) {
                    const float* p = (const float*)srcv + (size_t)r * K + ko;
                    float4 f0 = *reinterpret_cast<const float4*>(p);
                    float4 f1 = *reinterpret_cast<const float4*>(p + 4);
                    v[0] = (short)f2bf(f0.x); v[1] = (short)f2bf(f0.y);
                    v[2] = (short)f2bf(f0.z); v[3] = (short)f2bf(f0.w);
                    v[4] = (short)f2bf(f1.x); v[5] = (short)f2bf(f1.y);
                    v[6] = (short)f2bf(f1.z); v[7] = (short)f2bf(f1.w);
                } else {
                    v = *reinterpret_cast<const short8*>(
                        (const ushort*)srcv + (size_t)r * K + ko);
                }
            }
            a[mf][kb] = v;
        }
    }

    // ---- MFMA: 8 n-frags x 2 m-frags x KB ----
    f32x4 acc[8][2];
    #pragma unroll
    for (int nf = 0; nf < 8; ++nf) {
        acc[nf][0] = f32x4{0.f, 0.f, 0.f, 0.f};
        acc[nf][1] = f32x4{0.f, 0.f, 0.f, 0.f};
    }
    #pragma unroll
    for (int nf = 0; nf < 8; ++nf) {
        #pragma unroll
        for (int kb = 0; kb < KB; ++kb) {
            short8 b = *reinterpret_cast<const short8*>(
                &Wt[(size_t)(nf * 16 + l15) * K + kb * 32 + lhi * 8]);
            acc[nf][0] = __builtin_amdgcn_mfma_f32_16x16x32_bf16(a[0][kb], b, acc[nf][0], 0, 0, 0);
            acc[nf][1] = __builtin_amdgcn_mfma_f32_16x16x32_bf16(a[1][kb], b, acc[nf][1], 0, 0, 0);
        }
    }

    // ---- epilogue: C/D layout col = l15, row = lhi*4 + j ----
    #pragma unroll
    for (int mf = 0; mf < 2; ++mf) {
        #pragma unroll
        for (int j = 0; j < 4; ++j) {
            int m = rowbase + mf * 16 + lhi * 4 + j;
            if (m >= M) continue;
            float ev = 0.f, d = 1.f;
            if (EXTRA) ev = (m < extraLimit) ? extraVal[m] : 0.f;
            if (SCALE) d = dinv[m];
            #pragma unroll
            for (int nf = 0; nf < 8; ++nf) {
                int n = nf * 16 + l15;
                float v = acc[nf][mf][j];
                if (EXTRA)  v += ev * Wex[n];
                if (BIAS)   v += bias[n];
                if (SCALE)  v *= d;
                if (OUTF32) ((float*)dstv)[(size_t)m * HN + n] = v;
                else        ((ushort*)dstv)[(size_t)m * HN + n] = f2bf(v);
            }
        }
    }
}

// out[i,:] = bf16( relu( dinv[i]*(sum_{e in in(i)} T[csr[e],:] + 2*T[i,:]) + bias ) )
__global__ __launch_bounds__(256) void gather_kernel(
    const int* __restrict__ off, const int* __restrict__ csr,
    const ushort* __restrict__ T, const float* __restrict__ dinv,
    const float* __restrict__ bias,
    ushort* __restrict__ out, int N)
{
    int gid = blockIdx.x * blockDim.x + threadIdx.x;
    int i = gid >> 4, lane = gid & 15;
    if (i >= N) return;
    int e = off[i], e1 = off[i + 1];
    float acc[8] = {0.f, 0.f, 0.f, 0.f, 0.f, 0.f, 0.f, 0.f};
    for (; e + 4 <= e1; e += 4) {
        int s0 = csr[e], s1 = csr[e + 1], s2 = csr[e + 2], s3 = csr[e + 3];
        short8 v0 = *reinterpret_cast<const short8*>(T + (size_t)s0 * HN + lane * 8);
        short8 v1 = *reinterpret_cast<const short8*>(T + (size_t)s1 * HN + lane * 8);
        short8 v2 = *reinterpret_cast<const short8*>(T + (size_t)s2 * HN + lane * 8);
        short8 v3 = *reinterpret_cast<const short8*>(T + (size_t)s3 * HN + lane * 8);
        #pragma unroll
        for (int j = 0; j < 8; ++j)
            acc[j] += (bf2f((ushort)v0[j]) + bf2f((ushort)v1[j]))
                    + (bf2f((ushort)v2[j]) + bf2f((ushort)v3[j]));
    }
    for (; e < e1; ++e) {
        int s = csr[e];
        short8 v = *reinterpret_cast<const short8*>(T + (size_t)s * HN + lane * 8);
        #pragma unroll
        for (int j = 0; j < 8; ++j) acc[j] += bf2f((ushort)v[j]);
    }
    short8 t = *reinterpret_cast<const short8*>(T + (size_t)i * HN + lane * 8);
    float d = dinv[i];
    float4 b0 = *reinterpret_cast<const float4*>(bias + lane * 8);
    float4 b1 = *reinterpret_cast<const float4*>(bias + lane * 8 + 4);
    float bb[8] = {b0.x, b0.y, b0.z, b0.w, b1.x, b1.y, b1.z, b1.w};
    short8 o;
    #pragma unroll
    for (int j = 0; j < 8; ++j) {
        float v = d * (acc[j] + 2.f * bf2f((ushort)t[j])) + bb[j];
        o[j] = (short)f2bf(fmaxf(v, 0.f));
    }
    *reinterpret_cast<short8*>(out + (size_t)i * HN + lane * 8) = o;
}

inline int cdiv(int a, int b) { return (a + b - 1) / b; }

} // namespace

extern "C" void kernel_launch(void* const* d_in, const int* in_sizes, int n_in,
                              void* d_out, int out_size, void* d_ws, size_t ws_size,
                              hipStream_t stream)
{
    const float* x       = (const float*)d_in[0];
    const float* W_down0 = (const float*)d_in[2];
    const float* b_down0 = (const float*)d_in[3];
    const float* W_down1 = (const float*)d_in[4];
    const float* b_down1 = (const float*)d_in[5];
    const float* W_up0   = (const float*)d_in[6];
    const float* b_up0   = (const float*)d_in[7];
    const float* W_up1   = (const float*)d_in[8];
    const float* b_up1   = (const float*)d_in[9];
    const float* W_lin   = (const float*)d_in[10];
    const float* b_lin   = (const float*)d_in[11];
    const int*   ei0     = (const int*)d_in[12];
    const int*   ei1     = (const int*)d_in[13];
    const int*   ei2     = (const int*)d_in[14];
    const int*   perm1   = (const int*)d_in[15];
    const int*   perm2   = (const int*)d_in[16];

    char* ws = (char*)d_ws;
    size_t o = 0;
    auto carve = [&](size_t bytes) { void* p = ws + o; o += (bytes + 15) & ~size_t(15); return p; };

    ushort* X    = (ushort*)carve((size_t)N0 * HN * 2);   // activations (bf16)
    ushort* T    = (ushort*)carve((size_t)N0 * HN * 2);   // gemm out / gather in (bf16)
    ushort* Wt0  = (ushort*)carve((size_t)HN * CIN * 2);  // transposed weights
    ushort* Wt1  = (ushort*)carve((size_t)HN * HN * 2);
    ushort* Wt2  = (ushort*)carve((size_t)HN * HN * 2);
    ushort* Wt3  = (ushort*)carve((size_t)HN * HN * 2);
    ushort* Wt4  = (ushort*)carve((size_t)HN * HN * 2);
    // contiguous zero block
    size_t zero_off = o;
    int*   cnt0  = (int*)  carve((size_t)N0 * 4);
    int*   cnt1  = (int*)  carve((size_t)N1 * 4);
    int*   cur0  = (int*)  carve((size_t)N0 * 4);
    int*   cur1  = (int*)  carve((size_t)N1 * 4);
    float* cntE  = (float*)carve((size_t)N2 * 4);
    size_t zero_bytes = o - zero_off;
    // contiguous 0xFF block
    size_t ff_off = o;
    int*   inv1  = (int*)  carve((size_t)N0 * 4);
    int*   inv2  = (int*)  carve((size_t)N1 * 4);
    size_t ff_bytes = o - ff_off;
    float* dinv0 = (float*)carve((size_t)N0 * 4);
    float* dinv1 = (float*)carve((size_t)N1 * 4);
    int*   off0  = (int*)  carve((size_t)(N0 + 1) * 4);
    int*   off1  = (int*)  carve((size_t)(N1 + 1) * 4);
    int*   csr0  = (int*)  carve((size_t)E0 * 4);
    int*   csr1  = (int*)  carve((size_t)E1 * 4);

    hipMemsetAsync(ws + zero_off, 0,    zero_bytes, stream);
    hipMemsetAsync(ws + ff_off,   0xFF, ff_bytes,   stream);

    // ---- setup: degrees, inverse perms, CSR, transposed bf16 weights ----
    hist_int_kernel<<<cdiv(E0, 256), 256, 0, stream>>>(ei0 + E0, E0, cnt0);
    hist_int_kernel<<<cdiv(E1, 256), 256, 0, stream>>>(ei1 + E1, E1, cnt1);
    hist_f_kernel<<<cdiv(2 * E2, 256), 256, 0, stream>>>(ei2, 2 * E2, cntE);
    dinv_kernel<<<cdiv(N0, 256), 256, 0, stream>>>(cnt0, dinv0, N0);
    dinv_kernel<<<cdiv(N1, 256), 256, 0, stream>>>(cnt1, dinv1, N1);
    invperm_kernel<<<cdiv(N1, 256), 256, 0, stream>>>(perm1, N1, inv1);
    invperm_kernel<<<cdiv(N2, 256), 256, 0, stream>>>(perm2, N2, inv2);
    wprep_kernel<<<dim3(64, 5), 256, 0, stream>>>(W_down0, W_down1, W_up0, W_up1, W_lin,
                                                  Wt0, Wt1, Wt2, Wt3, Wt4);
    scan2_kernel<<<2, 1024, 0, stream>>>(cnt0, N0, off0, cnt1, N1, off1);
    fill_kernel<<<cdiv(E0, 256), 256, 0, stream>>>(ei0, ei0 + E0, E0, off0, cur0, csr0);
    fill_kernel<<<cdiv(E1, 256), 256, 0, stream>>>(ei1, ei1 + E1, E1, off1, cur1, csr1);

    // ---- L0: T = dinv0*(x @ W_down0); X = gather(relu, b_down0) ----
    mfma_gemm_kernel<CIN, 0, true, false, false, true, false>
        <<<cdiv(N0, 128), 256, 0, stream>>>(
        x, nullptr, nullptr, 0, nullptr, Wt0, nullptr, dinv0, T, N0);
    gather_kernel<<<cdiv(N0 * 16, 256), 256, 0, stream>>>(off0, csr0, T, dinv0, b_down0, X, N0);

    // ---- L1: T = dinv1*(X[perm1] @ W_down1); X = gather ----
    mfma_gemm_kernel<HN, 1, false, false, false, true, false>
        <<<cdiv(N1, 128), 256, 0, stream>>>(
        X, perm1, nullptr, 0, nullptr, Wt1, nullptr, dinv1, T, N1);
    gather_kernel<<<cdiv(N1 * 16, 256), 256, 0, stream>>>(off1, csr1, T, dinv1, b_down1, X, N1);

    // ---- L2: T = dinv1*(unpool2(X) @ W_up0 + degE*Wex); X = gather ----
    mfma_gemm_kernel<HN, 2, false, true, false, true, false>
        <<<cdiv(N1, 128), 256, 0, stream>>>(
        X, inv2, cntE, N2, W_up0 + 128 * HN, Wt2, nullptr, dinv1, T, N1);
    gather_kernel<<<cdiv(N1 * 16, 256), 256, 0, stream>>>(off1, csr1, T, dinv1, b_up0, X, N1);

    // ---- L3: T = dinv0*(unpool1(X) @ W_up1 + degE*Wex); X = gather ----
    mfma_gemm_kernel<HN, 1, false, true, false, true, false>
        <<<cdiv(N0, 128), 256, 0, stream>>>(
        X, inv1, cntE, N2, W_up1 + 128 * HN, Wt3, nullptr, dinv0, T, N0);
    gather_kernel<<<cdiv(N0 * 16, 256), 256, 0, stream>>>(off0, csr0, T, dinv0, b_up1, X, N0);

    // ---- final: d_out = X @ W_lin + b_lin (f32 out, no memcpy) ----
    mfma_gemm_kernel<HN, 0, false, false, true, false, true>
        <<<cdiv(N0, 128), 256, 0, stream>>>(
        X, nullptr, nullptr, 0, nullptr, Wt4, b_lin, nullptr, d_out, N0);
}

// Round 4
// 381.599 us; speedup vs baseline: 15.7289x; 1.3373x over previous
//
#include <hip/hip_runtime.h>
#include <hip/hip_bf16.h>

namespace {

constexpr int HN  = 128;
constexpr int N0  = 80000, N1 = 60000, N2 = 45000;
constexpr int CIN = 64;
constexpr int E0  = 1280000, E1 = 360000, E2 = 315000;

constexpr int NB0 = (N0 + 255) / 256;   // 313
constexpr int NB1 = (N1 + 255) / 256;   // 235

using short8 = __attribute__((ext_vector_type(8))) short;
using f32x4  = __attribute__((ext_vector_type(4))) float;

__device__ inline ushort f2bf(float f) {
    uint u = __float_as_uint(f);
    u += 0x7fffu + ((u >> 16) & 1u);
    return (ushort)(u >> 16);
}
__device__ inline float bf2f(ushort u) {
    return __uint_as_float(((uint)u) << 16);
}

// ---- setup: one pass over all 3 edge lists; records per-edge slot for csr fill ----
__global__ __launch_bounds__(256) void histpos_kernel(
    const int* __restrict__ ei0, const int* __restrict__ ei1, const int* __restrict__ ei2,
    int* __restrict__ cnt0, int* __restrict__ cnt1, float* __restrict__ cntE,
    int* __restrict__ pos0, int* __restrict__ pos1)
{
    int g = blockIdx.x * 256 + threadIdx.x;
    if (g < E0) {
        pos0[g] = atomicAdd(&cnt0[ei0[E0 + g]], 1);
    } else if (g < E0 + E1) {
        int e = g - E0;
        pos1[e] = atomicAdd(&cnt1[ei1[E1 + e]], 1);
    } else {
        int e = g - E0 - E1;
        if (e < 2 * E2) unsafeAtomicAdd(&cntE[ei2[e]], 1.0f);
    }
}

// dinv + inverse perms in one launch
__global__ __launch_bounds__(256) void misc_kernel(
    const int* __restrict__ cnt0, const int* __restrict__ cnt1,
    const int* __restrict__ perm1, const int* __restrict__ perm2,
    float* __restrict__ dinv0, float* __restrict__ dinv1,
    int* __restrict__ inv1, int* __restrict__ inv2)
{
    int i = blockIdx.x * 256 + threadIdx.x;
    if (i < N0) dinv0[i] = rsqrtf((float)cnt0[i] + 2.0f);
    if (i < N1) dinv1[i] = rsqrtf((float)cnt1[i] + 2.0f);
    if (i < N1) inv1[perm1[i]] = i;
    if (i < N2) inv2[perm2[i]] = i;
}

// transpose+convert the 5 weight matrices: Wt[n][k] = bf16(W[k][n])
__global__ void wprep_kernel(const float* W0, const float* W1, const float* W2,
                             const float* W3, const float* W4,
                             ushort* T0, ushort* T1, ushort* T2, ushort* T3, ushort* T4)
{
    int m = blockIdx.y;
    const float* W; ushort* T; int K;
    switch (m) {
        case 0: W = W0; T = T0; K = CIN; break;
        case 1: W = W1; T = T1; K = HN;  break;
        case 2: W = W2; T = T2; K = HN;  break;
        case 3: W = W3; T = T3; K = HN;  break;
        default: W = W4; T = T4; K = HN; break;
    }
    int idx = blockIdx.x * 256 + threadIdx.x;
    if (idx >= K * HN) return;
    int n = idx / K, k = idx - n * K;
    T[idx] = f2bf(W[k * HN + n]);
}

// ---- hierarchical exclusive scan over cnt0 (NB0 chunks) and cnt1 (NB1 chunks) ----
__global__ __launch_bounds__(256) void scan_p1(const int* __restrict__ cnt0,
                                               const int* __restrict__ cnt1,
                                               int* __restrict__ bsum)
{
    int b = blockIdx.x;
    const int* src; int n, base;
    if (b < NB0) { src = cnt0; n = N0; base = b * 256; }
    else         { src = cnt1; n = N1; base = (b - NB0) * 256; }
    int i = base + threadIdx.x;
    int v = (i < n) ? src[i] : 0;
    #pragma unroll
    for (int d = 1; d < 64; d <<= 1) v += __shfl_xor(v, d, 64);
    __shared__ int ws[4];
    if ((threadIdx.x & 63) == 0) ws[threadIdx.x >> 6] = v;
    __syncthreads();
    if (threadIdx.x == 0) bsum[b] = ws[0] + ws[1] + ws[2] + ws[3];
}

__global__ void scan_p2(int* __restrict__ bsum) {
    int seg = blockIdx.x;
    int s = seg ? NB0 : 0, n = seg ? NB1 : NB0;
    int lane = threadIdx.x;
    int carry = 0;
    for (int base = 0; base < n; base += 64) {
        int v = (base + lane < n) ? bsum[s + base + lane] : 0;
        int sc = v;
        #pragma unroll
        for (int d = 1; d < 64; d <<= 1) {
            int t = __shfl_up(sc, d, 64);
            if (lane >= d) sc += t;
        }
        if (base + lane < n) bsum[s + base + lane] = carry + sc - v;
        carry += __shfl(sc, 63, 64);
    }
}

__global__ __launch_bounds__(256) void scan_p3(const int* __restrict__ cnt0,
                                               const int* __restrict__ cnt1,
                                               const int* __restrict__ bsum,
                                               int* __restrict__ off0,
                                               int* __restrict__ off1)
{
    int b = blockIdx.x;
    const int* src; int* off; int n, base;
    if (b < NB0) { src = cnt0; off = off0; n = N0; base = b * 256; }
    else         { src = cnt1; off = off1; n = N1; base = (b - NB0) * 256; }
    int tid = threadIdx.x, lane = tid & 63, w = tid >> 6;
    int i = base + tid;
    int v = (i < n) ? src[i] : 0;
    int sc = v;
    #pragma unroll
    for (int d = 1; d < 64; d <<= 1) {
        int t = __shfl_up(sc, d, 64);
        if (lane >= d) sc += t;
    }
    __shared__ int ws[4];
    if (lane == 63) ws[w] = sc;
    __syncthreads();
    int wb = 0;
    for (int k = 0; k < w; ++k) wb += ws[k];
    if (i < n) off[i] = bsum[b] + wb + sc - v;
    if (b == 0 && tid == 0) { off0[N0] = E0; off1[N1] = E1; }
}

// atomic-free csr fill for both levels in one launch
__global__ __launch_bounds__(256) void fill2_kernel(
    const int* __restrict__ ei0, const int* __restrict__ ei1,
    const int* __restrict__ off0, const int* __restrict__ off1,
    const int* __restrict__ pos0, const int* __restrict__ pos1,
    int* __restrict__ csr0, int* __restrict__ csr1)
{
    int g = blockIdx.x * 256 + threadIdx.x;
    if (g < E0) {
        int c = ei0[E0 + g];
        csr0[off0[c] + pos0[g]] = ei0[g];
    } else {
        int e = g - E0;
        if (e < E1) {
            int c = ei1[E1 + e];
            csr1[off1[c] + pos1[e]] = ei1[e];
        }
    }
}

// dst[i,:] = src_row(i) @ W (+extraVal[i]*Wex) (+bias) (*dinv[i] if SCALE)
// MODE 0: row i; MODE 1: r=rowidx[i] (>=0 else zero row); MODE 2: zero unless rowidx[i]>=0.
template<int K, int MODE, bool AF32, bool EXTRA, bool BIAS, bool SCALE, bool OUTF32>
__global__ __launch_bounds__(256) void mfma_gemm_kernel(
    const void* __restrict__ srcv,
    const int* __restrict__ rowidx,
    const float* __restrict__ extraVal, int extraLimit,
    const float* __restrict__ Wex,
    const ushort* __restrict__ Wt,
    const float* __restrict__ bias,
    const float* __restrict__ dinv,
    void* __restrict__ dstv, int M)
{
    constexpr int KB = K / 32;
    const int tid  = threadIdx.x;
    const int wid  = tid >> 6, lane = tid & 63;
    const int l15  = lane & 15, lhi = lane >> 4;
    const int rowbase = blockIdx.x * 128 + wid * 32;

    short8 a[2][KB];
    #pragma unroll
    for (int mf = 0; mf < 2; ++mf) {
        int i = rowbase + mf * 16 + l15;
        int r = -1;
        if (i < M) {
            if (MODE == 0) r = i;
            else if (MODE == 1) r = rowidx[i];
            else r = (rowidx[i] >= 0) ? i : -1;
        }
        #pragma unroll
        for (int kb = 0; kb < KB; ++kb) {
            int ko = kb * 32 + lhi * 8;
            short8 v = {0, 0, 0, 0, 0, 0, 0, 0};
            if (r >= 0) {
                if (AF32) {
                    const float* p = (const float*)srcv + (size_t)r * K + ko;
                    float4 f0 = *reinterpret_cast<const float4*>(p);
                    float4 f1 = *reinterpret_cast<const float4*>(p + 4);
                    v[0] = (short)f2bf(f0.x); v[1] = (short)f2bf(f0.y);
                    v[2] = (short)f2bf(f0.z); v[3] = (short)f2bf(f0.w);
                    v[4] = (short)f2bf(f1.x); v[5] = (short)f2bf(f1.y);
                    v[6] = (short)f2bf(f1.z); v[7] = (short)f2bf(f1.w);
                } else {
                    v = *reinterpret_cast<const short8*>(
                        (const ushort*)srcv + (size_t)r * K + ko);
                }
            }
            a[mf][kb] = v;
        }
    }

    f32x4 acc[8][2];
    #pragma unroll
    for (int nf = 0; nf < 8; ++nf) {
        acc[nf][0] = f32x4{0.f, 0.f, 0.f, 0.f};
        acc[nf][1] = f32x4{0.f, 0.f, 0.f, 0.f};
    }
    #pragma unroll
    for (int nf = 0; nf < 8; ++nf) {
        #pragma unroll
        for (int kb = 0; kb < KB; ++kb) {
            short8 b = *reinterpret_cast<const short8*>(
                &Wt[(size_t)(nf * 16 + l15) * K + kb * 32 + lhi * 8]);
            acc[nf][0] = __builtin_amdgcn_mfma_f32_16x16x32_bf16(a[0][kb], b, acc[nf][0], 0, 0, 0);
            acc[nf][1] = __builtin_amdgcn_mfma_f32_16x16x32_bf16(a[1][kb], b, acc[nf][1], 0, 0, 0);
        }
    }

    #pragma unroll
    for (int mf = 0; mf < 2; ++mf) {
        #pragma unroll
        for (int j = 0; j < 4; ++j) {
            int m = rowbase + mf * 16 + lhi * 4 + j;
            if (m >= M) continue;
            float ev = 0.f, d = 1.f;
            if (EXTRA) ev = (m < extraLimit) ? extraVal[m] : 0.f;
            if (SCALE) d = dinv[m];
            #pragma unroll
            for (int nf = 0; nf < 8; ++nf) {
                int n = nf * 16 + l15;
                float v = acc[nf][mf][j];
                if (EXTRA)  v += ev * Wex[n];
                if (BIAS)   v += bias[n];
                if (SCALE)  v *= d;
                if (OUTF32) ((float*)dstv)[(size_t)m * HN + n] = v;
                else        ((ushort*)dstv)[(size_t)m * HN + n] = f2bf(v);
            }
        }
    }
}

// out[i,:] = bf16( relu( dinv[i]*(sum_in T[csr[e],:] + 2*T[i,:]) + bias ) )
__global__ __launch_bounds__(256) void gather_kernel(
    const int* __restrict__ off, const int* __restrict__ csr,
    const ushort* __restrict__ T, const float* __restrict__ dinv,
    const float* __restrict__ bias,
    ushort* __restrict__ out, int N)
{
    int gid = blockIdx.x * blockDim.x + threadIdx.x;
    int i = gid >> 4, lane = gid & 15;
    if (i >= N) return;
    int e = off[i], e1 = off[i + 1];
    float acc[8] = {0.f, 0.f, 0.f, 0.f, 0.f, 0.f, 0.f, 0.f};
    for (; e + 4 <= e1; e += 4) {
        int s0 = csr[e], s1 = csr[e + 1], s2 = csr[e + 2], s3 = csr[e + 3];
        short8 v0 = *reinterpret_cast<const short8*>(T + (size_t)s0 * HN + lane * 8);
        short8 v1 = *reinterpret_cast<const short8*>(T + (size_t)s1 * HN + lane * 8);
        short8 v2 = *reinterpret_cast<const short8*>(T + (size_t)s2 * HN + lane * 8);
        short8 v3 = *reinterpret_cast<const short8*>(T + (size_t)s3 * HN + lane * 8);
        #pragma unroll
        for (int j = 0; j < 8; ++j)
            acc[j] += (bf2f((ushort)v0[j]) + bf2f((ushort)v1[j]))
                    + (bf2f((ushort)v2[j]) + bf2f((ushort)v3[j]));
    }
    for (; e < e1; ++e) {
        int s = csr[e];
        short8 v = *reinterpret_cast<const short8*>(T + (size_t)s * HN + lane * 8);
        #pragma unroll
        for (int j = 0; j < 8; ++j) acc[j] += bf2f((ushort)v[j]);
    }
    short8 t = *reinterpret_cast<const short8*>(T + (size_t)i * HN + lane * 8);
    float d = dinv[i];
    float4 b0 = *reinterpret_cast<const float4*>(bias + lane * 8);
    float4 b1 = *reinterpret_cast<const float4*>(bias + lane * 8 + 4);
    float bb[8] = {b0.x, b0.y, b0.z, b0.w, b1.x, b1.y, b1.z, b1.w};
    short8 o;
    #pragma unroll
    for (int j = 0; j < 8; ++j) {
        float v = d * (acc[j] + 2.f * bf2f((ushort)t[j])) + bb[j];
        o[j] = (short)f2bf(fmaxf(v, 0.f));
    }
    *reinterpret_cast<short8*>(out + (size_t)i * HN + lane * 8) = o;
}

inline int cdiv(int a, int b) { return (a + b - 1) / b; }

} // namespace

extern "C" void kernel_launch(void* const* d_in, const int* in_sizes, int n_in,
                              void* d_out, int out_size, void* d_ws, size_t ws_size,
                              hipStream_t stream)
{
    const float* x       = (const float*)d_in[0];
    const float* W_down0 = (const float*)d_in[2];
    const float* b_down0 = (const float*)d_in[3];
    const float* W_down1 = (const float*)d_in[4];
    const float* b_down1 = (const float*)d_in[5];
    const float* W_up0   = (const float*)d_in[6];
    const float* b_up0   = (const float*)d_in[7];
    const float* W_up1   = (const float*)d_in[8];
    const float* b_up1   = (const float*)d_in[9];
    const float* W_lin   = (const float*)d_in[10];
    const float* b_lin   = (const float*)d_in[11];
    const int*   ei0     = (const int*)d_in[12];
    const int*   ei1     = (const int*)d_in[13];
    const int*   ei2     = (const int*)d_in[14];
    const int*   perm1   = (const int*)d_in[15];
    const int*   perm2   = (const int*)d_in[16];

    char* ws = (char*)d_ws;
    size_t o = 0;
    auto carve = [&](size_t bytes) { void* p = ws + o; o += (bytes + 15) & ~size_t(15); return p; };

    ushort* X    = (ushort*)carve((size_t)N0 * HN * 2);   // activations (bf16)
    ushort* T    = (ushort*)carve((size_t)N0 * HN * 2);   // gemm out / gather in (bf16)
    ushort* Wt0  = (ushort*)carve((size_t)HN * CIN * 2);
    ushort* Wt1  = (ushort*)carve((size_t)HN * HN * 2);
    ushort* Wt2  = (ushort*)carve((size_t)HN * HN * 2);
    ushort* Wt3  = (ushort*)carve((size_t)HN * HN * 2);
    ushort* Wt4  = (ushort*)carve((size_t)HN * HN * 2);
    // contiguous zero block
    size_t zero_off = o;
    int*   cnt0  = (int*)  carve((size_t)N0 * 4);
    int*   cnt1  = (int*)  carve((size_t)N1 * 4);
    float* cntE  = (float*)carve((size_t)N2 * 4);
    size_t zero_bytes = o - zero_off;
    // contiguous 0xFF block
    size_t ff_off = o;
    int*   inv1  = (int*)  carve((size_t)N0 * 4);
    int*   inv2  = (int*)  carve((size_t)N1 * 4);
    size_t ff_bytes = o - ff_off;
    float* dinv0 = (float*)carve((size_t)N0 * 4);
    float* dinv1 = (float*)carve((size_t)N1 * 4);
    int*   off0  = (int*)  carve((size_t)(N0 + 1) * 4);
    int*   off1  = (int*)  carve((size_t)(N1 + 1) * 4);
    int*   csr0  = (int*)  carve((size_t)E0 * 4);
    int*   csr1  = (int*)  carve((size_t)E1 * 4);
    int*   bsum  = (int*)  carve((size_t)(NB0 + NB1) * 4);
    // pos arrays alias T (only live before first GEMM writes T)
    int*   pos0  = (int*)T;
    int*   pos1  = pos0 + E0;

    hipMemsetAsync(ws + zero_off, 0,    zero_bytes, stream);
    hipMemsetAsync(ws + ff_off,   0xFF, ff_bytes,   stream);

    // ---- setup ----
    histpos_kernel<<<cdiv(E0 + E1 + 2 * E2, 256), 256, 0, stream>>>(
        ei0, ei1, ei2, cnt0, cnt1, cntE, pos0, pos1);
    misc_kernel<<<cdiv(N0, 256), 256, 0, stream>>>(cnt0, cnt1, perm1, perm2,
                                                   dinv0, dinv1, inv1, inv2);
    wprep_kernel<<<dim3(64, 5), 256, 0, stream>>>(W_down0, W_down1, W_up0, W_up1, W_lin,
                                                  Wt0, Wt1, Wt2, Wt3, Wt4);
    scan_p1<<<NB0 + NB1, 256, 0, stream>>>(cnt0, cnt1, bsum);
    scan_p2<<<2, 64, 0, stream>>>(bsum);
    scan_p3<<<NB0 + NB1, 256, 0, stream>>>(cnt0, cnt1, bsum, off0, off1);
    fill2_kernel<<<cdiv(E0 + E1, 256), 256, 0, stream>>>(ei0, ei1, off0, off1,
                                                         pos0, pos1, csr0, csr1);

    // ---- L0 ----
    mfma_gemm_kernel<CIN, 0, true, false, false, true, false>
        <<<cdiv(N0, 128), 256, 0, stream>>>(
        x, nullptr, nullptr, 0, nullptr, Wt0, nullptr, dinv0, T, N0);
    gather_kernel<<<cdiv(N0 * 16, 256), 256, 0, stream>>>(off0, csr0, T, dinv0, b_down0, X, N0);

    // ---- L1 ----
    mfma_gemm_kernel<HN, 1, false, false, false, true, false>
        <<<cdiv(N1, 128), 256, 0, stream>>>(
        X, perm1, nullptr, 0, nullptr, Wt1, nullptr, dinv1, T, N1);
    gather_kernel<<<cdiv(N1 * 16, 256), 256, 0, stream>>>(off1, csr1, T, dinv1, b_down1, X, N1);

    // ---- L2 ----
    mfma_gemm_kernel<HN, 2, false, true, false, true, false>
        <<<cdiv(N1, 128), 256, 0, stream>>>(
        X, inv2, cntE, N2, W_up0 + 128 * HN, Wt2, nullptr, dinv1, T, N1);
    gather_kernel<<<cdiv(N1 * 16, 256), 256, 0, stream>>>(off1, csr1, T, dinv1, b_up0, X, N1);

    // ---- L3 ----
    mfma_gemm_kernel<HN, 1, false, true, false, true, false>
        <<<cdiv(N0, 128), 256, 0, stream>>>(
        X, inv1, cntE, N2, W_up1 + 128 * HN, Wt3, nullptr, dinv0, T, N0);
    gather_kernel<<<cdiv(N0 * 16, 256), 256, 0, stream>>>(off0, csr0, T, dinv0, b_up1, X, N0);

    // ---- final ----
    mfma_gemm_kernel<HN, 0, false, false, true, false, true>
        <<<cdiv(N0, 128), 256, 0, stream>>>(
        X, nullptr, nullptr, 0, nullptr, Wt4, b_lin, nullptr, d_out, N0);
}

// Round 5
// 344.485 us; speedup vs baseline: 17.4235x; 1.1077x over previous
//
#include <hip/hip_runtime.h>
#include <hip/hip_bf16.h>

namespace {

constexpr int HN  = 128;
constexpr int N0  = 80000, N1 = 60000, N2 = 45000;
constexpr int CIN = 64;
constexpr int E0  = 1280000, E1 = 360000, E2 = 315000;

constexpr int BSHIFT = 6;                 // 64 dst nodes per bucket
constexpr int BMASK  = 63;
constexpr int NBKT0  = (N0 + 63) / 64;    // 1250
constexpr int NBKT1  = (N1 + 63) / 64;    // 938
constexpr int CHUNK  = 8192;              // edges per partition block
constexpr int NBLK0  = (E0 + CHUNK - 1) / CHUNK;  // 157
constexpr int NBLK1  = (E1 + CHUNK - 1) / CHUNK;  // 44
constexpr int SRCCAP = 2560;              // LDS src list per gather bucket

using short8 = __attribute__((ext_vector_type(8))) short;
using f32x4  = __attribute__((ext_vector_type(4))) float;

__device__ inline ushort f2bf(float f) {
    uint u = __float_as_uint(f);
    u += 0x7fffu + ((u >> 16) & 1u);
    return (ushort)(u >> 16);
}
__device__ inline float bf2f(ushort u) {
    return __uint_as_float(((uint)u) << 16);
}

__device__ inline int wave_scan_incl(int v, int lane) {
    #pragma unroll
    for (int d = 1; d < 64; d <<= 1) {
        int t = __shfl_up(v, d, 64);
        if (lane >= d) v += t;
    }
    return v;
}

// y=0: E2 histogram (fire-and-forget); y=1: inverse perms; y=2: weight transpose->bf16
__global__ __launch_bounds__(256) void setup_small(
    const int* __restrict__ ei2, float* __restrict__ cntE,
    const int* __restrict__ perm1, const int* __restrict__ perm2,
    int* __restrict__ inv1, int* __restrict__ inv2,
    const float* __restrict__ W0, const float* __restrict__ W1,
    const float* __restrict__ W2, const float* __restrict__ W3,
    const float* __restrict__ W4,
    ushort* __restrict__ T0, ushort* __restrict__ T1, ushort* __restrict__ T2,
    ushort* __restrict__ T3, ushort* __restrict__ T4)
{
    int idx = blockIdx.x * 256 + threadIdx.x;
    if (blockIdx.y == 0) {
        if (idx < 2 * E2) unsafeAtomicAdd(&cntE[ei2[idx]], 1.0f);
    } else if (blockIdx.y == 1) {
        if (idx < N1) inv1[perm1[idx]] = idx;
        if (idx < N2) inv2[perm2[idx]] = idx;
    } else {
        if (idx >= CIN * HN + 4 * HN * HN) return;
        const float* W; ushort* T; int K, local;
        if (idx < CIN * HN) { W = W0; T = T0; K = CIN; local = idx; }
        else {
            int r = idx - CIN * HN;
            int m = r >> 14; local = r & 16383; K = HN;
            switch (m) { case 0: W = W1; T = T1; break; case 1: W = W2; T = T2; break;
                         case 2: W = W3; T = T3; break; default: W = W4; T = T4; break; }
        }
        int n = local / K, k = local - n * K;
        T[local] = f2bf(W[k * HN + n]);
    }
}

// per-(block,bucket) counts + bucket totals
__global__ __launch_bounds__(256) void count_pass(
    const int* __restrict__ ei0, const int* __restrict__ ei1,
    int* __restrict__ blkcnt, int* __restrict__ bkttot)
{
    __shared__ int cnt[NBKT0];
    int b = blockIdx.x;
    const int* dst; int E, NBKT, bl, coff, toff;
    if (b < NBLK0) { dst = ei0 + E0; E = E0; NBKT = NBKT0; bl = b; coff = 0; toff = 0; }
    else { dst = ei1 + E1; E = E1; NBKT = NBKT1; bl = b - NBLK0; coff = NBLK0 * NBKT0; toff = NBKT0; }
    int tid = threadIdx.x;
    for (int q = tid; q < NBKT; q += 256) cnt[q] = 0;
    __syncthreads();
    int base = bl * CHUNK;
    #pragma unroll 4
    for (int it = 0; it < CHUNK / 256; ++it) {
        int e = base + it * 256 + tid;
        if (e < E) atomicAdd(&cnt[dst[e] >> BSHIFT], 1);
    }
    __syncthreads();
    for (int q = tid; q < NBKT; q += 256) {
        int c = cnt[q];
        blkcnt[coff + bl * NBKT + q] = c;
        if (c) atomicAdd(&bkttot[toff + q], c);
    }
}

// exclusive scan of bucket totals per level (+ sentinel)
__global__ void scanB(const int* __restrict__ bkttot, int* __restrict__ bktbase) {
    int seg = blockIdx.x;
    int n = seg ? NBKT1 : NBKT0;
    const int* src = bkttot + (seg ? NBKT0 : 0);
    int* dst = bktbase + (seg ? NBKT0 + 1 : 0);
    int lane = threadIdx.x;
    int carry = 0;
    for (int base = 0; base < n; base += 64) {
        int v = (base + lane < n) ? src[base + lane] : 0;
        int inc = wave_scan_incl(v, lane);
        if (base + lane < n) dst[base + lane] = carry + inc - v;
        carry += __shfl(inc, 63, 64);
    }
    if (lane == 0) dst[n] = carry;
}

// per-bucket scan over blocks -> absolute output cursor per (block,bucket)
__global__ void scanC(const int* __restrict__ blkcnt, const int* __restrict__ bktbase,
                      int* __restrict__ blkoff)
{
    int qg = blockIdx.x;
    int NBKT, NBLK, coff, q, boff;
    if (qg < NBKT0) { NBKT = NBKT0; NBLK = NBLK0; coff = 0; q = qg; boff = 0; }
    else { NBKT = NBKT1; NBLK = NBLK1; coff = NBLK0 * NBKT0; q = qg - NBKT0; boff = NBKT0 + 1; }
    int lane = threadIdx.x;
    int basev = bktbase[boff + q];
    int carry = 0;
    for (int base = 0; base < NBLK; base += 64) {
        int b = base + lane;
        int v = (b < NBLK) ? blkcnt[coff + b * NBKT + q] : 0;
        int inc = wave_scan_incl(v, lane);
        if (b < NBLK) blkoff[coff + b * NBKT + q] = basev + carry + inc - v;
        carry += __shfl(inc, 63, 64);
    }
}

// LDS-staged radix partition: pairs[slot] = src | (dst&63)<<17, grouped by dst>>6
__global__ __launch_bounds__(256) void partition_pass(
    const int* __restrict__ ei0, const int* __restrict__ ei1,
    const int* __restrict__ blkoff,
    int* __restrict__ pairs0, int* __restrict__ pairs1)
{
    __shared__ int off[NBKT0 + 1];
    __shared__ int cur[NBKT0];
    __shared__ int gb2[NBKT0];
    __shared__ int lpk[CHUNK];
    __shared__ int lga[CHUNK];
    __shared__ int wpart[4];
    int b = blockIdx.x;
    const int* src; const int* dst; int* pairs; int E, NBKT, bl, coff;
    if (b < NBLK0) { src = ei0; dst = ei0 + E0; pairs = pairs0; E = E0; NBKT = NBKT0; bl = b; coff = 0; }
    else { src = ei1; dst = ei1 + E1; pairs = pairs1; E = E1; NBKT = NBKT1; bl = b - NBLK0; coff = NBLK0 * NBKT0; }
    int tid = threadIdx.x;
    for (int q = tid; q < NBKT; q += 256) cur[q] = 0;
    __syncthreads();
    int base = bl * CHUNK;
    #pragma unroll 4
    for (int it = 0; it < CHUNK / 256; ++it) {
        int e = base + it * 256 + tid;
        if (e < E) atomicAdd(&cur[dst[e] >> BSHIFT], 1);
    }
    __syncthreads();
    // block scan cur -> off
    {
        int carry = 0;
        int lane = tid & 63, w = tid >> 6;
        for (int bb = 0; bb < NBKT; bb += 256) {
            int v = (bb + tid < NBKT) ? cur[bb + tid] : 0;
            int inc = wave_scan_incl(v, lane);
            __syncthreads();
            if (lane == 63) wpart[w] = inc;
            __syncthreads();
            int woff = 0;
            #pragma unroll
            for (int k = 0; k < 4; ++k) if (k < w) woff += wpart[k];
            int tot = wpart[0] + wpart[1] + wpart[2] + wpart[3];
            if (bb + tid < NBKT) off[bb + tid] = carry + woff + inc - v;
            carry += tot;
        }
        if (tid == 0) off[NBKT] = carry;
    }
    __syncthreads();
    for (int q = tid; q < NBKT; q += 256) {
        cur[q] = off[q];
        gb2[q] = blkoff[coff + bl * NBKT + q] - off[q];
    }
    __syncthreads();
    #pragma unroll 4
    for (int it = 0; it < CHUNK / 256; ++it) {
        int e = base + it * 256 + tid;
        if (e < E) {
            int d = dst[e];
            int q = d >> BSHIFT;
            int s = atomicAdd(&cur[q], 1);
            lpk[s] = src[e] | ((d & BMASK) << 17);
            lga[s] = gb2[q] + s;
        }
    }
    __syncthreads();
    int cnt_tot = min(CHUNK, E - base);
    for (int s = tid; s < cnt_tot; s += 256)
        pairs[lga[s]] = lpk[s];
}

// per-node degree -> dinv, from partitioned pairs
__global__ __launch_bounds__(256) void degpass(
    const int* __restrict__ pairs0, const int* __restrict__ pairs1,
    const int* __restrict__ bktbase,
    float* __restrict__ dinv0, float* __restrict__ dinv1)
{
    __shared__ int cnt[64];
    int qg = blockIdx.x;
    const int* pairs; float* dinv; int q, boff, N;
    if (qg < NBKT0) { pairs = pairs0; dinv = dinv0; q = qg; boff = 0; N = N0; }
    else { pairs = pairs1; dinv = dinv1; q = qg - NBKT0; boff = NBKT0 + 1; N = N1; }
    int tid = threadIdx.x;
    if (tid < 64) cnt[tid] = 0;
    __syncthreads();
    int s0 = bktbase[boff + q], s1 = bktbase[boff + q + 1];
    for (int s = s0 + tid; s < s1; s += 256)
        atomicAdd(&cnt[(pairs[s] >> 17) & BMASK], 1);
    __syncthreads();
    int i = q * 64 + tid;
    if (tid < 64 && i < N) dinv[i] = rsqrtf((float)cnt[tid] + 2.0f);
}

// dst[i,:] = src_row(i) @ W (+extraVal[i]*Wex) (+bias) (*dinv[i] if SCALE)
template<int K, int MODE, bool AF32, bool EXTRA, bool BIAS, bool SCALE, bool OUTF32>
__global__ __launch_bounds__(256) void mfma_gemm_kernel(
    const void* __restrict__ srcv,
    const int* __restrict__ rowidx,
    const float* __restrict__ extraVal, int extraLimit,
    const float* __restrict__ Wex,
    const ushort* __restrict__ Wt,
    const float* __restrict__ bias,
    const float* __restrict__ dinv,
    void* __restrict__ dstv, int M)
{
    constexpr int KB = K / 32;
    const int tid  = threadIdx.x;
    const int wid  = tid >> 6, lane = tid & 63;
    const int l15  = lane & 15, lhi = lane >> 4;
    const int rowbase = blockIdx.x * 128 + wid * 32;

    short8 a[2][KB];
    #pragma unroll
    for (int mf = 0; mf < 2; ++mf) {
        int i = rowbase + mf * 16 + l15;
        int r = -1;
        if (i < M) {
            if (MODE == 0) r = i;
            else if (MODE == 1) r = rowidx[i];
            else r = (rowidx[i] >= 0) ? i : -1;
        }
        #pragma unroll
        for (int kb = 0; kb < KB; ++kb) {
            int ko = kb * 32 + lhi * 8;
            short8 v = {0, 0, 0, 0, 0, 0, 0, 0};
            if (r >= 0) {
                if (AF32) {
                    const float* p = (const float*)srcv + (size_t)r * K + ko;
                    float4 f0 = *reinterpret_cast<const float4*>(p);
                    float4 f1 = *reinterpret_cast<const float4*>(p + 4);
                    v[0] = (short)f2bf(f0.x); v[1] = (short)f2bf(f0.y);
                    v[2] = (short)f2bf(f0.z); v[3] = (short)f2bf(f0.w);
                    v[4] = (short)f2bf(f1.x); v[5] = (short)f2bf(f1.y);
                    v[6] = (short)f2bf(f1.z); v[7] = (short)f2bf(f1.w);
                } else {
                    v = *reinterpret_cast<const short8*>(
                        (const ushort*)srcv + (size_t)r * K + ko);
                }
            }
            a[mf][kb] = v;
        }
    }

    f32x4 acc[8][2];
    #pragma unroll
    for (int nf = 0; nf < 8; ++nf) {
        acc[nf][0] = f32x4{0.f, 0.f, 0.f, 0.f};
        acc[nf][1] = f32x4{0.f, 0.f, 0.f, 0.f};
    }
    #pragma unroll
    for (int nf = 0; nf < 8; ++nf) {
        #pragma unroll
        for (int kb = 0; kb < KB; ++kb) {
            short8 b = *reinterpret_cast<const short8*>(
                &Wt[(size_t)(nf * 16 + l15) * K + kb * 32 + lhi * 8]);
            acc[nf][0] = __builtin_amdgcn_mfma_f32_16x16x32_bf16(a[0][kb], b, acc[nf][0], 0, 0, 0);
            acc[nf][1] = __builtin_amdgcn_mfma_f32_16x16x32_bf16(a[1][kb], b, acc[nf][1], 0, 0, 0);
        }
    }

    #pragma unroll
    for (int mf = 0; mf < 2; ++mf) {
        #pragma unroll
        for (int j = 0; j < 4; ++j) {
            int m = rowbase + mf * 16 + lhi * 4 + j;
            if (m >= M) continue;
            float ev = 0.f, d = 1.f;
            if (EXTRA) ev = (m < extraLimit) ? extraVal[m] : 0.f;
            if (SCALE) d = dinv[m];
            #pragma unroll
            for (int nf = 0; nf < 8; ++nf) {
                int n = nf * 16 + l15;
                float v = acc[nf][mf][j];
                if (EXTRA)  v += ev * Wex[n];
                if (BIAS)   v += bias[n];
                if (SCALE)  v *= d;
                if (OUTF32) ((float*)dstv)[(size_t)m * HN + n] = v;
                else        ((ushort*)dstv)[(size_t)m * HN + n] = f2bf(v);
            }
        }
    }
}

// one 64-dst bucket per block: build CSR in LDS, then gather features
__global__ __launch_bounds__(256) void gather_kernel(
    const int* __restrict__ pairs, const int* __restrict__ bktbase,
    const ushort* __restrict__ T, const float* __restrict__ bias,
    ushort* __restrict__ out, int N)
{
    __shared__ int cnt[64];
    __shared__ int off[65];
    __shared__ int srcs[SRCCAP];
    int q = blockIdx.x;
    int tid = threadIdx.x;
    if (tid < 64) cnt[tid] = 0;
    __syncthreads();
    int s0 = bktbase[q], s1 = bktbase[q + 1];
    for (int s = s0 + tid; s < s1; s += 256)
        atomicAdd(&cnt[(pairs[s] >> 17) & BMASK], 1);
    __syncthreads();
    if (tid < 64) {
        int v = cnt[tid];
        int inc = wave_scan_incl(v, tid);
        off[tid] = inc - v;
        if (tid == 63) off[64] = inc;
    }
    __syncthreads();
    if (tid < 64) cnt[tid] = off[tid];
    __syncthreads();
    for (int s = s0 + tid; s < s1; s += 256) {
        int pk = pairs[s];
        int p = atomicAdd(&cnt[(pk >> 17) & BMASK], 1);
        srcs[p < SRCCAP ? p : SRCCAP - 1] = pk & 0x1FFFF;
    }
    __syncthreads();

    int g = tid >> 4, lane = tid & 15;
    float4 b0 = *reinterpret_cast<const float4*>(bias + lane * 8);
    float4 b1 = *reinterpret_cast<const float4*>(bias + lane * 8 + 4);
    float bb[8] = {b0.x, b0.y, b0.z, b0.w, b1.x, b1.y, b1.z, b1.w};
    for (int dd = g; dd < 64; dd += 16) {
        int i = q * 64 + dd;
        if (i >= N) continue;
        int e = off[dd], e1 = off[dd + 1];
        float dv = rsqrtf((float)(e1 - e) + 2.0f);
        float acc[8] = {0.f, 0.f, 0.f, 0.f, 0.f, 0.f, 0.f, 0.f};
        for (; e + 4 <= e1; e += 4) {
            int sa = srcs[e], sb = srcs[e + 1], sc = srcs[e + 2], sd = srcs[e + 3];
            short8 va = *reinterpret_cast<const short8*>(T + (size_t)sa * HN + lane * 8);
            short8 vb = *reinterpret_cast<const short8*>(T + (size_t)sb * HN + lane * 8);
            short8 vc = *reinterpret_cast<const short8*>(T + (size_t)sc * HN + lane * 8);
            short8 vd = *reinterpret_cast<const short8*>(T + (size_t)sd * HN + lane * 8);
            #pragma unroll
            for (int j = 0; j < 8; ++j)
                acc[j] += (bf2f((ushort)va[j]) + bf2f((ushort)vb[j]))
                        + (bf2f((ushort)vc[j]) + bf2f((ushort)vd[j]));
        }
        for (; e < e1; ++e) {
            int s = srcs[e];
            short8 v = *reinterpret_cast<const short8*>(T + (size_t)s * HN + lane * 8);
            #pragma unroll
            for (int j = 0; j < 8; ++j) acc[j] += bf2f((ushort)v[j]);
        }
        short8 t8 = *reinterpret_cast<const short8*>(T + (size_t)i * HN + lane * 8);
        short8 o;
        #pragma unroll
        for (int j = 0; j < 8; ++j) {
            float v = dv * (acc[j] + 2.f * bf2f((ushort)t8[j])) + bb[j];
            o[j] = (short)f2bf(fmaxf(v, 0.f));
        }
        *reinterpret_cast<short8*>(out + (size_t)i * HN + lane * 8) = o;
    }
}

inline int cdiv(int a, int b) { return (a + b - 1) / b; }

} // namespace

extern "C" void kernel_launch(void* const* d_in, const int* in_sizes, int n_in,
                              void* d_out, int out_size, void* d_ws, size_t ws_size,
                              hipStream_t stream)
{
    const float* x       = (const float*)d_in[0];
    const float* W_down0 = (const float*)d_in[2];
    const float* b_down0 = (const float*)d_in[3];
    const float* W_down1 = (const float*)d_in[4];
    const float* b_down1 = (const float*)d_in[5];
    const float* W_up0   = (const float*)d_in[6];
    const float* b_up0   = (const float*)d_in[7];
    const float* W_up1   = (const float*)d_in[8];
    const float* b_up1   = (const float*)d_in[9];
    const float* W_lin   = (const float*)d_in[10];
    const float* b_lin   = (const float*)d_in[11];
    const int*   ei0     = (const int*)d_in[12];
    const int*   ei1     = (const int*)d_in[13];
    const int*   ei2     = (const int*)d_in[14];
    const int*   perm1   = (const int*)d_in[15];
    const int*   perm2   = (const int*)d_in[16];

    char* ws = (char*)d_ws;
    size_t o = 0;
    auto carve = [&](size_t bytes) { void* p = ws + o; o += (bytes + 15) & ~size_t(15); return p; };

    ushort* X     = (ushort*)carve((size_t)N0 * HN * 2);
    ushort* T     = (ushort*)carve((size_t)N0 * HN * 2);
    ushort* Wt0   = (ushort*)carve((size_t)HN * CIN * 2);
    ushort* Wt1   = (ushort*)carve((size_t)HN * HN * 2);
    ushort* Wt2   = (ushort*)carve((size_t)HN * HN * 2);
    ushort* Wt3   = (ushort*)carve((size_t)HN * HN * 2);
    ushort* Wt4   = (ushort*)carve((size_t)HN * HN * 2);
    int*    pairs0 = (int*)carve((size_t)E0 * 4);
    int*    pairs1 = (int*)carve((size_t)E1 * 4);
    int*    blkcnt = (int*)carve((size_t)(NBLK0 * NBKT0 + NBLK1 * NBKT1) * 4);
    int*    blkoff = (int*)carve((size_t)(NBLK0 * NBKT0 + NBLK1 * NBKT1) * 4);
    int*    bktbase = (int*)carve((size_t)(NBKT0 + NBKT1 + 2) * 4);
    float*  dinv0 = (float*)carve((size_t)N0 * 4);
    float*  dinv1 = (float*)carve((size_t)N1 * 4);
    // contiguous zero block
    size_t zero_off = o;
    int*    bkttot = (int*)carve((size_t)(NBKT0 + NBKT1) * 4);
    float*  cntE   = (float*)carve((size_t)N2 * 4);
    size_t zero_bytes = o - zero_off;
    // contiguous 0xFF block
    size_t ff_off = o;
    int*    inv1 = (int*)carve((size_t)N0 * 4);
    int*    inv2 = (int*)carve((size_t)N1 * 4);
    size_t ff_bytes = o - ff_off;

    hipMemsetAsync(ws + zero_off, 0,    zero_bytes, stream);
    hipMemsetAsync(ws + ff_off,   0xFF, ff_bytes,   stream);

    // ---- setup ----
    setup_small<<<dim3(cdiv(2 * E2, 256), 3), 256, 0, stream>>>(
        ei2, cntE, perm1, perm2, inv1, inv2,
        W_down0, W_down1, W_up0, W_up1, W_lin, Wt0, Wt1, Wt2, Wt3, Wt4);
    count_pass<<<NBLK0 + NBLK1, 256, 0, stream>>>(ei0, ei1, blkcnt, bkttot);
    scanB<<<2, 64, 0, stream>>>(bkttot, bktbase);
    scanC<<<NBKT0 + NBKT1, 64, 0, stream>>>(blkcnt, bktbase, blkoff);
    partition_pass<<<NBLK0 + NBLK1, 256, 0, stream>>>(ei0, ei1, blkoff, pairs0, pairs1);
    degpass<<<NBKT0 + NBKT1, 256, 0, stream>>>(pairs0, pairs1, bktbase, dinv0, dinv1);

    const int* bktbase1 = bktbase + NBKT0 + 1;

    // ---- L0 ----
    mfma_gemm_kernel<CIN, 0, true, false, false, true, false>
        <<<cdiv(N0, 128), 256, 0, stream>>>(
        x, nullptr, nullptr, 0, nullptr, Wt0, nullptr, dinv0, T, N0);
    gather_kernel<<<NBKT0, 256, 0, stream>>>(pairs0, bktbase, T, b_down0, X, N0);

    // ---- L1 ----
    mfma_gemm_kernel<HN, 1, false, false, false, true, false>
        <<<cdiv(N1, 128), 256, 0, stream>>>(
        X, perm1, nullptr, 0, nullptr, Wt1, nullptr, dinv1, T, N1);
    gather_kernel<<<NBKT1, 256, 0, stream>>>(pairs1, bktbase1, T, b_down1, X, N1);

    // ---- L2 ----
    mfma_gemm_kernel<HN, 2, false, true, false, true, false>
        <<<cdiv(N1, 128), 256, 0, stream>>>(
        X, inv2, cntE, N2, W_up0 + 128 * HN, Wt2, nullptr, dinv1, T, N1);
    gather_kernel<<<NBKT1, 256, 0, stream>>>(pairs1, bktbase1, T, b_up0, X, N1);

    // ---- L3 ----
    mfma_gemm_kernel<HN, 1, false, true, false, true, false>
        <<<cdiv(N0, 128), 256, 0, stream>>>(
        X, inv1, cntE, N2, W_up1 + 128 * HN, Wt3, nullptr, dinv0, T, N0);
    gather_kernel<<<NBKT0, 256, 0, stream>>>(pairs0, bktbase, T, b_up1, X, N0);

    // ---- final ----
    mfma_gemm_kernel<HN, 0, false, false, true, false, true>
        <<<cdiv(N0, 128), 256, 0, stream>>>(
        X, nullptr, nullptr, 0, nullptr, Wt4, b_lin, nullptr, d_out, N0);
}

// Round 6
// 325.495 us; speedup vs baseline: 18.4399x; 1.0583x over previous
//
#include <hip/hip_runtime.h>
#include <hip/hip_bf16.h>

namespace {

constexpr int HN  = 128;
constexpr int N0  = 80000, N1 = 60000, N2 = 45000;
constexpr int CIN = 64;
constexpr int E0  = 1280000, E1 = 360000, E2 = 315000;

constexpr int BSHIFT = 6;                 // 64 dst nodes per bucket
constexpr int BMASK  = 63;
constexpr int NBKT0  = (N0 + 63) / 64;    // 1250
constexpr int NBKT1  = (N1 + 63) / 64;    // 938
constexpr int CHUNK  = 8192;              // edges per partition block
constexpr int NBLK0  = (E0 + CHUNK - 1) / CHUNK;  // 157
constexpr int NBLK1  = (E1 + CHUNK - 1) / CHUNK;  // 44
constexpr int SRCCAP = 2560;              // LDS staging per bucket (max ~1150 actual)

using short8  = __attribute__((ext_vector_type(8))) short;
using short4v = __attribute__((ext_vector_type(4))) short;
using f32x4   = __attribute__((ext_vector_type(4))) float;

template<int C> struct VecT;
template<> struct VecT<8> { using T = short8; };
template<> struct VecT<4> { using T = short4v; };

__device__ inline ushort f2bf(float f) {
    uint u = __float_as_uint(f);
    u += 0x7fffu + ((u >> 16) & 1u);
    return (ushort)(u >> 16);
}
__device__ inline float bf2f(ushort u) {
    return __uint_as_float(((uint)u) << 16);
}

__device__ inline int wave_scan_incl(int v, int lane) {
    #pragma unroll
    for (int d = 1; d < 64; d <<= 1) {
        int t = __shfl_up(v, d, 64);
        if (lane >= d) v += t;
    }
    return v;
}

// y=0: E2 histogram; y=1: inverse perms; y=2: weight transpose->bf16
__global__ __launch_bounds__(256) void setup_small(
    const int* __restrict__ ei2, float* __restrict__ cntE,
    const int* __restrict__ perm1, const int* __restrict__ perm2,
    int* __restrict__ inv1, int* __restrict__ inv2,
    const float* __restrict__ W0, const float* __restrict__ W1,
    const float* __restrict__ W2, const float* __restrict__ W3,
    const float* __restrict__ W4,
    ushort* __restrict__ T0, ushort* __restrict__ T1, ushort* __restrict__ T2,
    ushort* __restrict__ T3, ushort* __restrict__ T4)
{
    int idx = blockIdx.x * 256 + threadIdx.x;
    if (blockIdx.y == 0) {
        if (idx < 2 * E2) unsafeAtomicAdd(&cntE[ei2[idx]], 1.0f);
    } else if (blockIdx.y == 1) {
        if (idx < N1) inv1[perm1[idx]] = idx;
        if (idx < N2) inv2[perm2[idx]] = idx;
    } else {
        if (idx >= CIN * HN + 4 * HN * HN) return;
        const float* W; ushort* T; int K, local;
        if (idx < CIN * HN) { W = W0; T = T0; K = CIN; local = idx; }
        else {
            int r = idx - CIN * HN;
            int m = r >> 14; local = r & 16383; K = HN;
            switch (m) { case 0: W = W1; T = T1; break; case 1: W = W2; T = T2; break;
                         case 2: W = W3; T = T3; break; default: W = W4; T = T4; break; }
        }
        int n = local / K, k = local - n * K;
        T[local] = f2bf(W[k * HN + n]);
    }
}

// per-(block,bucket) counts + bucket totals
__global__ __launch_bounds__(256) void count_pass(
    const int* __restrict__ ei0, const int* __restrict__ ei1,
    int* __restrict__ blkcnt, int* __restrict__ bkttot)
{
    __shared__ int cnt[NBKT0];
    int b = blockIdx.x;
    const int* dst; int E, NBKT, bl, coff, toff;
    if (b < NBLK0) { dst = ei0 + E0; E = E0; NBKT = NBKT0; bl = b; coff = 0; toff = 0; }
    else { dst = ei1 + E1; E = E1; NBKT = NBKT1; bl = b - NBLK0; coff = NBLK0 * NBKT0; toff = NBKT0; }
    int tid = threadIdx.x;
    for (int q = tid; q < NBKT; q += 256) cnt[q] = 0;
    __syncthreads();
    int base = bl * CHUNK;
    #pragma unroll 4
    for (int it = 0; it < CHUNK / 256; ++it) {
        int e = base + it * 256 + tid;
        if (e < E) atomicAdd(&cnt[dst[e] >> BSHIFT], 1);
    }
    __syncthreads();
    for (int q = tid; q < NBKT; q += 256) {
        int c = cnt[q];
        blkcnt[coff + bl * NBKT + q] = c;
        if (c) atomicAdd(&bkttot[toff + q], c);
    }
}

// exclusive scan of bucket totals per level (+ sentinel)
__global__ void scanB(const int* __restrict__ bkttot, int* __restrict__ bktbase) {
    int seg = blockIdx.x;
    int n = seg ? NBKT1 : NBKT0;
    const int* src = bkttot + (seg ? NBKT0 : 0);
    int* dst = bktbase + (seg ? NBKT0 + 1 : 0);
    int lane = threadIdx.x;
    int carry = 0;
    for (int base = 0; base < n; base += 64) {
        int v = (base + lane < n) ? src[base + lane] : 0;
        int inc = wave_scan_incl(v, lane);
        if (base + lane < n) dst[base + lane] = carry + inc - v;
        carry += __shfl(inc, 63, 64);
    }
    if (lane == 0) dst[n] = carry;
}

// per-bucket scan over blocks -> absolute output cursor per (block,bucket)
__global__ void scanC(const int* __restrict__ blkcnt, const int* __restrict__ bktbase,
                      int* __restrict__ blkoff)
{
    int qg = blockIdx.x;
    int NBKT, NBLK, coff, q, boff;
    if (qg < NBKT0) { NBKT = NBKT0; NBLK = NBLK0; coff = 0; q = qg; boff = 0; }
    else { NBKT = NBKT1; NBLK = NBLK1; coff = NBLK0 * NBKT0; q = qg - NBKT0; boff = NBKT0 + 1; }
    int lane = threadIdx.x;
    int basev = bktbase[boff + q];
    int carry = 0;
    for (int base = 0; base < NBLK; base += 64) {
        int b = base + lane;
        int v = (b < NBLK) ? blkcnt[coff + b * NBKT + q] : 0;
        int inc = wave_scan_incl(v, lane);
        if (b < NBLK) blkoff[coff + b * NBKT + q] = basev + carry + inc - v;
        carry += __shfl(inc, 63, 64);
    }
}

// LDS-staged radix partition: pairs[slot] = src | (dst&63)<<17, grouped by dst>>6
__global__ __launch_bounds__(256) void partition_pass(
    const int* __restrict__ ei0, const int* __restrict__ ei1,
    const int* __restrict__ blkoff,
    int* __restrict__ pairs0, int* __restrict__ pairs1)
{
    __shared__ int off[NBKT0 + 1];
    __shared__ int cur[NBKT0];
    __shared__ int gb2[NBKT0];
    __shared__ int lpk[CHUNK];
    __shared__ int lga[CHUNK];
    __shared__ int wpart[4];
    int b = blockIdx.x;
    const int* src; const int* dst; int* pairs; int E, NBKT, bl, coff;
    if (b < NBLK0) { src = ei0; dst = ei0 + E0; pairs = pairs0; E = E0; NBKT = NBKT0; bl = b; coff = 0; }
    else { src = ei1; dst = ei1 + E1; pairs = pairs1; E = E1; NBKT = NBKT1; bl = b - NBLK0; coff = NBLK0 * NBKT0; }
    int tid = threadIdx.x;
    for (int q = tid; q < NBKT; q += 256) cur[q] = 0;
    __syncthreads();
    int base = bl * CHUNK;
    #pragma unroll 4
    for (int it = 0; it < CHUNK / 256; ++it) {
        int e = base + it * 256 + tid;
        if (e < E) atomicAdd(&cur[dst[e] >> BSHIFT], 1);
    }
    __syncthreads();
    {
        int carry = 0;
        int lane = tid & 63, w = tid >> 6;
        for (int bb = 0; bb < NBKT; bb += 256) {
            int v = (bb + tid < NBKT) ? cur[bb + tid] : 0;
            int inc = wave_scan_incl(v, lane);
            __syncthreads();
            if (lane == 63) wpart[w] = inc;
            __syncthreads();
            int woff = 0;
            #pragma unroll
            for (int k = 0; k < 4; ++k) if (k < w) woff += wpart[k];
            int tot = wpart[0] + wpart[1] + wpart[2] + wpart[3];
            if (bb + tid < NBKT) off[bb + tid] = carry + woff + inc - v;
            carry += tot;
        }
        if (tid == 0) off[NBKT] = carry;
    }
    __syncthreads();
    for (int q = tid; q < NBKT; q += 256) {
        cur[q] = off[q];
        gb2[q] = blkoff[coff + bl * NBKT + q] - off[q];
    }
    __syncthreads();
    #pragma unroll 4
    for (int it = 0; it < CHUNK / 256; ++it) {
        int e = base + it * 256 + tid;
        if (e < E) {
            int d = dst[e];
            int q = d >> BSHIFT;
            int s = atomicAdd(&cur[q], 1);
            lpk[s] = src[e] | ((d & BMASK) << 17);
            lga[s] = gb2[q] + s;
        }
    }
    __syncthreads();
    int cnt_tot = min(CHUNK, E - base);
    for (int s = tid; s < cnt_tot; s += 256)
        pairs[lga[s]] = lpk[s];
}

// per-bucket counting sort: pairs (bucket-grouped) -> node-ordered src lists (in place),
// global node offsets noff[N+1], dinv. Level-0 blocks also emit xs = bf16(dinv0*x).
__global__ __launch_bounds__(256) void sort_pass(
    int* __restrict__ pairs0, int* __restrict__ pairs1,
    const int* __restrict__ bktbase,
    float* __restrict__ dinv0, float* __restrict__ dinv1,
    int* __restrict__ noff0, int* __restrict__ noff1,
    const float* __restrict__ x, ushort* __restrict__ xs)
{
    __shared__ int lpk[SRCCAP];
    __shared__ int cnt[64];
    __shared__ int cur[64];
    __shared__ float dvl[64];
    int qg = blockIdx.x;
    int* pairs; float* dinv; int* noff; int q, boff, N, nbkt;
    bool lvl0 = qg < NBKT0;
    if (lvl0) { pairs = pairs0; dinv = dinv0; noff = noff0; q = qg; boff = 0; N = N0; nbkt = NBKT0; }
    else { pairs = pairs1; dinv = dinv1; noff = noff1; q = qg - NBKT0; boff = NBKT0 + 1; N = N1; nbkt = NBKT1; }
    int tid = threadIdx.x;
    if (tid < 64) cnt[tid] = 0;
    __syncthreads();
    int s0 = bktbase[boff + q], s1 = bktbase[boff + q + 1];
    int m = min(s1 - s0, SRCCAP);
    for (int s = tid; s < m; s += 256) {
        int pk = pairs[s0 + s];
        lpk[s] = pk;
        atomicAdd(&cnt[(pk >> 17) & BMASK], 1);
    }
    __syncthreads();
    if (tid < 64) {
        int v = cnt[tid];
        int inc = wave_scan_incl(v, tid);
        cur[tid] = inc - v;
        dvl[tid] = rsqrtf((float)v + 2.0f);
        int i = q * 64 + tid;
        if (i < N) {
            dinv[i] = dvl[tid];
            noff[i] = s0 + inc - v;
        }
        if (q == nbkt - 1 && tid == 0) noff[N] = s1;
    }
    __syncthreads();
    for (int s = tid; s < m; s += 256) {
        int pk = lpk[s];
        int p = atomicAdd(&cur[(pk >> 17) & BMASK], 1);
        pairs[s0 + p] = pk & 0x1FFFF;
    }
    if (lvl0) {
        for (int idx = tid; idx < 64 * 64; idx += 256) {
            int nl = idx >> 6, col = idx & 63;
            size_t i = (size_t)q * 64 + nl;          // N0 == 1250*64, always in range
            xs[i * CIN + col] = f2bf(dvl[nl] * x[i * CIN + col]);
        }
    }
}

// dst[i,:] = src_row(i) @ W (+extraVal[i]*Wex) (+bias) (*dinv[i] if SCALE) (relu if RELU)
template<int K, int MODE, bool AF32, bool EXTRA, bool BIAS, bool SCALE, bool RELU, bool OUTF32>
__global__ __launch_bounds__(256) void mfma_gemm_kernel(
    const void* __restrict__ srcv,
    const int* __restrict__ rowidx,
    const float* __restrict__ extraVal, int extraLimit,
    const float* __restrict__ Wex,
    const ushort* __restrict__ Wt,
    const float* __restrict__ bias,
    const float* __restrict__ dinv,
    void* __restrict__ dstv, int M)
{
    constexpr int KB = K / 32;
    const int tid  = threadIdx.x;
    const int wid  = tid >> 6, lane = tid & 63;
    const int l15  = lane & 15, lhi = lane >> 4;
    const int rowbase = blockIdx.x * 128 + wid * 32;

    short8 a[2][KB];
    #pragma unroll
    for (int mf = 0; mf < 2; ++mf) {
        int i = rowbase + mf * 16 + l15;
        int r = -1;
        if (i < M) {
            if (MODE == 0) r = i;
            else if (MODE == 1) r = rowidx[i];
            else r = (rowidx[i] >= 0) ? i : -1;
        }
        #pragma unroll
        for (int kb = 0; kb < KB; ++kb) {
            int ko = kb * 32 + lhi * 8;
            short8 v = {0, 0, 0, 0, 0, 0, 0, 0};
            if (r >= 0) {
                if (AF32) {
                    const float* p = (const float*)srcv + (size_t)r * K + ko;
                    float4 f0 = *reinterpret_cast<const float4*>(p);
                    float4 f1 = *reinterpret_cast<const float4*>(p + 4);
                    v[0] = (short)f2bf(f0.x); v[1] = (short)f2bf(f0.y);
                    v[2] = (short)f2bf(f0.z); v[3] = (short)f2bf(f0.w);
                    v[4] = (short)f2bf(f1.x); v[5] = (short)f2bf(f1.y);
                    v[6] = (short)f2bf(f1.z); v[7] = (short)f2bf(f1.w);
                } else {
                    v = *reinterpret_cast<const short8*>(
                        (const ushort*)srcv + (size_t)r * K + ko);
                }
            }
            a[mf][kb] = v;
        }
    }

    f32x4 acc[8][2];
    #pragma unroll
    for (int nf = 0; nf < 8; ++nf) {
        acc[nf][0] = f32x4{0.f, 0.f, 0.f, 0.f};
        acc[nf][1] = f32x4{0.f, 0.f, 0.f, 0.f};
    }
    #pragma unroll
    for (int nf = 0; nf < 8; ++nf) {
        #pragma unroll
        for (int kb = 0; kb < KB; ++kb) {
            short8 b = *reinterpret_cast<const short8*>(
                &Wt[(size_t)(nf * 16 + l15) * K + kb * 32 + lhi * 8]);
            acc[nf][0] = __builtin_amdgcn_mfma_f32_16x16x32_bf16(a[0][kb], b, acc[nf][0], 0, 0, 0);
            acc[nf][1] = __builtin_amdgcn_mfma_f32_16x16x32_bf16(a[1][kb], b, acc[nf][1], 0, 0, 0);
        }
    }

    #pragma unroll
    for (int mf = 0; mf < 2; ++mf) {
        #pragma unroll
        for (int j = 0; j < 4; ++j) {
            int m = rowbase + mf * 16 + lhi * 4 + j;
            if (m >= M) continue;
            float ev = 0.f, d = 1.f;
            if (EXTRA) ev = (m < extraLimit) ? extraVal[m] : 0.f;
            if (SCALE) d = dinv[m];
            #pragma unroll
            for (int nf = 0; nf < 8; ++nf) {
                int n = nf * 16 + l15;
                float v = acc[nf][mf][j];
                if (EXTRA)  v += ev * Wex[n];
                if (BIAS)   v += bias[n];
                if (SCALE)  v *= d;
                if (RELU)   v = fmaxf(v, 0.f);
                if (OUTF32) ((float*)dstv)[(size_t)m * HN + n] = v;
                else        ((ushort*)dstv)[(size_t)m * HN + n] = f2bf(v);
            }
        }
    }
}

// flat gather via node-sorted csr/noff.
// BIASRELU: out = bf16(relu(dv*(sum + 2*T[i]) + bias)); else out = bf16(dv*(sum + 2*T[i]))
template<int DIM, bool BIASRELU>
__global__ __launch_bounds__(256) void gather_kernel(
    const int* __restrict__ noff, const int* __restrict__ csr,
    const ushort* __restrict__ T, const float* __restrict__ bias,
    ushort* __restrict__ out, int N)
{
    constexpr int C = DIM / 16;
    using V = typename VecT<C>::T;
    int gid = blockIdx.x * 256 + threadIdx.x;
    int i = gid >> 4, lane = gid & 15;
    if (i >= N) return;
    int e = noff[i], e1 = noff[i + 1];
    float dv = rsqrtf((float)(e1 - e) + 2.0f);
    float acc[C];
    #pragma unroll
    for (int j = 0; j < C; ++j) acc[j] = 0.f;
    for (; e + 4 <= e1; e += 4) {
        int sa = csr[e], sb = csr[e + 1], sc = csr[e + 2], sd = csr[e + 3];
        V va = *reinterpret_cast<const V*>(T + (size_t)sa * DIM + lane * C);
        V vb = *reinterpret_cast<const V*>(T + (size_t)sb * DIM + lane * C);
        V vc = *reinterpret_cast<const V*>(T + (size_t)sc * DIM + lane * C);
        V vd = *reinterpret_cast<const V*>(T + (size_t)sd * DIM + lane * C);
        #pragma unroll
        for (int j = 0; j < C; ++j)
            acc[j] += (bf2f((ushort)va[j]) + bf2f((ushort)vb[j]))
                    + (bf2f((ushort)vc[j]) + bf2f((ushort)vd[j]));
    }
    for (; e < e1; ++e) {
        int s = csr[e];
        V v = *reinterpret_cast<const V*>(T + (size_t)s * DIM + lane * C);
        #pragma unroll
        for (int j = 0; j < C; ++j) acc[j] += bf2f((ushort)v[j]);
    }
    V t = *reinterpret_cast<const V*>(T + (size_t)i * DIM + lane * C);
    V o;
    #pragma unroll
    for (int j = 0; j < C; ++j) {
        float v = dv * (acc[j] + 2.f * bf2f((ushort)t[j]));
        if (BIASRELU) v = fmaxf(v + bias[lane * C + j], 0.f);
        o[j] = (short)f2bf(v);
    }
    *reinterpret_cast<V*>(out + (size_t)i * DIM + lane * C) = o;
}

inline int cdiv(int a, int b) { return (a + b - 1) / b; }

} // namespace

extern "C" void kernel_launch(void* const* d_in, const int* in_sizes, int n_in,
                              void* d_out, int out_size, void* d_ws, size_t ws_size,
                              hipStream_t stream)
{
    const float* x       = (const float*)d_in[0];
    const float* W_down0 = (const float*)d_in[2];
    const float* b_down0 = (const float*)d_in[3];
    const float* W_down1 = (const float*)d_in[4];
    const float* b_down1 = (const float*)d_in[5];
    const float* W_up0   = (const float*)d_in[6];
    const float* b_up0   = (const float*)d_in[7];
    const float* W_up1   = (const float*)d_in[8];
    const float* b_up1   = (const float*)d_in[9];
    const float* W_lin   = (const float*)d_in[10];
    const float* b_lin   = (const float*)d_in[11];
    const int*   ei0     = (const int*)d_in[12];
    const int*   ei1     = (const int*)d_in[13];
    const int*   ei2     = (const int*)d_in[14];
    const int*   perm1   = (const int*)d_in[15];
    const int*   perm2   = (const int*)d_in[16];

    char* ws = (char*)d_ws;
    size_t o = 0;
    auto carve = [&](size_t bytes) { void* p = ws + o; o += (bytes + 15) & ~size_t(15); return p; };

    ushort* X     = (ushort*)carve((size_t)N0 * HN * 2);
    ushort* T     = (ushort*)carve((size_t)N0 * HN * 2);
    ushort* Wt0   = (ushort*)carve((size_t)HN * CIN * 2);
    ushort* Wt1   = (ushort*)carve((size_t)HN * HN * 2);
    ushort* Wt2   = (ushort*)carve((size_t)HN * HN * 2);
    ushort* Wt3   = (ushort*)carve((size_t)HN * HN * 2);
    ushort* Wt4   = (ushort*)carve((size_t)HN * HN * 2);
    int*    pairs0 = (int*)carve((size_t)E0 * 4);
    int*    pairs1 = (int*)carve((size_t)E1 * 4);
    int*    blkcnt = (int*)carve((size_t)(NBLK0 * NBKT0 + NBLK1 * NBKT1) * 4);
    int*    blkoff = (int*)carve((size_t)(NBLK0 * NBKT0 + NBLK1 * NBKT1) * 4);
    int*    bktbase = (int*)carve((size_t)(NBKT0 + NBKT1 + 2) * 4);
    float*  dinv0 = (float*)carve((size_t)N0 * 4);
    float*  dinv1 = (float*)carve((size_t)N1 * 4);
    int*    noff0 = (int*)carve((size_t)(N0 + 1) * 4);
    int*    noff1 = (int*)carve((size_t)(N1 + 1) * 4);
    // contiguous zero block
    size_t zero_off = o;
    int*    bkttot = (int*)carve((size_t)(NBKT0 + NBKT1) * 4);
    float*  cntE   = (float*)carve((size_t)N2 * 4);
    size_t zero_bytes = o - zero_off;
    // contiguous 0xFF block
    size_t ff_off = o;
    int*    inv1 = (int*)carve((size_t)N0 * 4);
    int*    inv2 = (int*)carve((size_t)N1 * 4);
    size_t ff_bytes = o - ff_off;

    // xs (N0 x 64 bf16) and a (N0 x 64 bf16) alias T (dead until L1 GEMM writes T)
    ushort* xs = T;
    ushort* agg = T + (size_t)N0 * CIN;

    hipMemsetAsync(ws + zero_off, 0,    zero_bytes, stream);
    hipMemsetAsync(ws + ff_off,   0xFF, ff_bytes,   stream);

    // ---- setup ----
    setup_small<<<dim3(cdiv(2 * E2, 256), 3), 256, 0, stream>>>(
        ei2, cntE, perm1, perm2, inv1, inv2,
        W_down0, W_down1, W_up0, W_up1, W_lin, Wt0, Wt1, Wt2, Wt3, Wt4);
    count_pass<<<NBLK0 + NBLK1, 256, 0, stream>>>(ei0, ei1, blkcnt, bkttot);
    scanB<<<2, 64, 0, stream>>>(bkttot, bktbase);
    scanC<<<NBKT0 + NBKT1, 64, 0, stream>>>(blkcnt, bktbase, blkoff);
    partition_pass<<<NBLK0 + NBLK1, 256, 0, stream>>>(ei0, ei1, blkoff, pairs0, pairs1);
    sort_pass<<<NBKT0 + NBKT1, 256, 0, stream>>>(pairs0, pairs1, bktbase,
                                                 dinv0, dinv1, noff0, noff1, x, xs);

    // ---- L0 (aggregate-first): agg = dv0*(sum xs[src] + 2*xs[i]); X = relu(agg@W_down0 + b) ----
    gather_kernel<CIN, false><<<cdiv(N0 * 16, 256), 256, 0, stream>>>(
        noff0, pairs0, xs, nullptr, agg, N0);
    mfma_gemm_kernel<CIN, 0, false, false, true, false, true, false>
        <<<cdiv(N0, 128), 256, 0, stream>>>(
        agg, nullptr, nullptr, 0, nullptr, Wt0, b_down0, nullptr, X, N0);

    // ---- L1 ----
    mfma_gemm_kernel<HN, 1, false, false, false, true, false, false>
        <<<cdiv(N1, 128), 256, 0, stream>>>(
        X, perm1, nullptr, 0, nullptr, Wt1, nullptr, dinv1, T, N1);
    gather_kernel<HN, true><<<cdiv(N1 * 16, 256), 256, 0, stream>>>(
        noff1, pairs1, T, b_down1, X, N1);

    // ---- L2 ----
    mfma_gemm_kernel<HN, 2, false, true, false, true, false, false>
        <<<cdiv(N1, 128), 256, 0, stream>>>(
        X, inv2, cntE, N2, W_up0 + 128 * HN, Wt2, nullptr, dinv1, T, N1);
    gather_kernel<HN, true><<<cdiv(N1 * 16, 256), 256, 0, stream>>>(
        noff1, pairs1, T, b_up0, X, N1);

    // ---- L3 ----
    mfma_gemm_kernel<HN, 1, false, true, false, true, false, false>
        <<<cdiv(N0, 128), 256, 0, stream>>>(
        X, inv1, cntE, N2, W_up1 + 128 * HN, Wt3, nullptr, dinv0, T, N0);
    gather_kernel<HN, true><<<cdiv(N0 * 16, 256), 256, 0, stream>>>(
        noff0, pairs0, T, b_up1, X, N0);

    // ---- final ----
    mfma_gemm_kernel<HN, 0, false, false, true, false, false, true>
        <<<cdiv(N0, 128), 256, 0, stream>>>(
        X, nullptr, nullptr, 0, nullptr, Wt4, b_lin, nullptr, d_out, N0);
}

// Round 7
// 303.562 us; speedup vs baseline: 19.7723x; 1.0723x over previous
//
#include <hip/hip_runtime.h>
#include <hip/hip_bf16.h>

namespace {

constexpr int HN  = 128;
constexpr int N0  = 80000, N1 = 60000, N2 = 45000;
constexpr int CIN = 64;
constexpr int E0  = 1280000, E1 = 360000, E2 = 315000;

constexpr int BSHIFT = 6;                 // 64 dst nodes per bucket
constexpr int BMASK  = 63;
constexpr int NBKT0  = (N0 + 63) / 64;    // 1250
constexpr int NBKT1  = (N1 + 63) / 64;    // 938
constexpr int CHUNK  = 8192;              // edges per partition block
constexpr int NBLK0  = (E0 + CHUNK - 1) / CHUNK;  // 157
constexpr int NBLK1  = (E1 + CHUNK - 1) / CHUNK;  // 44
constexpr int SRCCAP = 2560;              // LDS staging per bucket

using short8  = __attribute__((ext_vector_type(8))) short;
using short4v = __attribute__((ext_vector_type(4))) short;
using f32x4   = __attribute__((ext_vector_type(4))) float;

__device__ inline ushort f2bf(float f) {
    uint u = __float_as_uint(f);
    u += 0x7fffu + ((u >> 16) & 1u);
    return (ushort)(u >> 16);
}
__device__ inline float bf2f(ushort u) {
    return __uint_as_float(((uint)u) << 16);
}

__device__ inline int wave_scan_incl(int v, int lane) {
    #pragma unroll
    for (int d = 1; d < 64; d <<= 1) {
        int t = __shfl_up(v, d, 64);
        if (lane >= d) v += t;
    }
    return v;
}

// y=0: E2 histogram (fire-and-forget float atomics; integer-exact); y=1: weight transpose->bf16
__global__ __launch_bounds__(256) void setup_small(
    const int* __restrict__ ei2, float* __restrict__ cntE,
    const float* __restrict__ W0, const float* __restrict__ W1,
    const float* __restrict__ W2, const float* __restrict__ W3,
    const float* __restrict__ W4,
    ushort* __restrict__ T0, ushort* __restrict__ T1, ushort* __restrict__ T2,
    ushort* __restrict__ T3, ushort* __restrict__ T4)
{
    int idx = blockIdx.x * 256 + threadIdx.x;
    if (blockIdx.y == 0) {
        if (idx < 2 * E2) unsafeAtomicAdd(&cntE[ei2[idx]], 1.0f);
    } else {
        if (idx >= CIN * HN + 4 * HN * HN) return;
        const float* W; ushort* T; int K, local;
        if (idx < CIN * HN) { W = W0; T = T0; K = CIN; local = idx; }
        else {
            int r = idx - CIN * HN;
            int m = r >> 14; local = r & 16383; K = HN;
            switch (m) { case 0: W = W1; T = T1; break; case 1: W = W2; T = T2; break;
                         case 2: W = W3; T = T3; break; default: W = W4; T = T4; break; }
        }
        int n = local / K, k = local - n * K;
        T[local] = f2bf(W[k * HN + n]);
    }
}

// per-(block,bucket) counts + bucket totals
__global__ __launch_bounds__(256) void count_pass(
    const int* __restrict__ ei0, const int* __restrict__ ei1,
    int* __restrict__ blkcnt, int* __restrict__ bkttot)
{
    __shared__ int cnt[NBKT0];
    int b = blockIdx.x;
    const int* dst; int E, NBKT, bl, coff, toff;
    if (b < NBLK0) { dst = ei0 + E0; E = E0; NBKT = NBKT0; bl = b; coff = 0; toff = 0; }
    else { dst = ei1 + E1; E = E1; NBKT = NBKT1; bl = b - NBLK0; coff = NBLK0 * NBKT0; toff = NBKT0; }
    int tid = threadIdx.x;
    for (int q = tid; q < NBKT; q += 256) cnt[q] = 0;
    __syncthreads();
    int base = bl * CHUNK;
    #pragma unroll 4
    for (int it = 0; it < CHUNK / 256; ++it) {
        int e = base + it * 256 + tid;
        if (e < E) atomicAdd(&cnt[dst[e] >> BSHIFT], 1);
    }
    __syncthreads();
    for (int q = tid; q < NBKT; q += 256) {
        int c = cnt[q];
        blkcnt[coff + bl * NBKT + q] = c;
        if (c) atomicAdd(&bkttot[toff + q], c);
    }
}

// exclusive scan of bucket totals per level (+ sentinel)
__global__ void scanB(const int* __restrict__ bkttot, int* __restrict__ bktbase) {
    int seg = blockIdx.x;
    int n = seg ? NBKT1 : NBKT0;
    const int* src = bkttot + (seg ? NBKT0 : 0);
    int* dst = bktbase + (seg ? NBKT0 + 1 : 0);
    int lane = threadIdx.x;
    int carry = 0;
    for (int base = 0; base < n; base += 64) {
        int v = (base + lane < n) ? src[base + lane] : 0;
        int inc = wave_scan_incl(v, lane);
        if (base + lane < n) dst[base + lane] = carry + inc - v;
        carry += __shfl(inc, 63, 64);
    }
    if (lane == 0) dst[n] = carry;
}

// per-bucket scan over blocks -> absolute output cursor per (block,bucket)
__global__ void scanC(const int* __restrict__ blkcnt, const int* __restrict__ bktbase,
                      int* __restrict__ blkoff)
{
    int qg = blockIdx.x;
    int NBKT, NBLK, coff, q, boff;
    if (qg < NBKT0) { NBKT = NBKT0; NBLK = NBLK0; coff = 0; q = qg; boff = 0; }
    else { NBKT = NBKT1; NBLK = NBLK1; coff = NBLK0 * NBKT0; q = qg - NBKT0; boff = NBKT0 + 1; }
    int lane = threadIdx.x;
    int basev = bktbase[boff + q];
    int carry = 0;
    for (int base = 0; base < NBLK; base += 64) {
        int b = base + lane;
        int v = (b < NBLK) ? blkcnt[coff + b * NBKT + q] : 0;
        int inc = wave_scan_incl(v, lane);
        if (b < NBLK) blkoff[coff + b * NBKT + q] = basev + carry + inc - v;
        carry += __shfl(inc, 63, 64);
    }
}

// LDS-staged radix partition: pairs[slot] = src | (dst&63)<<17, grouped by dst>>6
__global__ __launch_bounds__(256) void partition_pass(
    const int* __restrict__ ei0, const int* __restrict__ ei1,
    const int* __restrict__ blkoff,
    int* __restrict__ pairs0, int* __restrict__ pairs1)
{
    __shared__ int off[NBKT0 + 1];
    __shared__ int cur[NBKT0];
    __shared__ int gb2[NBKT0];
    __shared__ int lpk[CHUNK];
    __shared__ int lga[CHUNK];
    __shared__ int wpart[4];
    int b = blockIdx.x;
    const int* src; const int* dst; int* pairs; int E, NBKT, bl, coff;
    if (b < NBLK0) { src = ei0; dst = ei0 + E0; pairs = pairs0; E = E0; NBKT = NBKT0; bl = b; coff = 0; }
    else { src = ei1; dst = ei1 + E1; pairs = pairs1; E = E1; NBKT = NBKT1; bl = b - NBLK0; coff = NBLK0 * NBKT0; }
    int tid = threadIdx.x;
    for (int q = tid; q < NBKT; q += 256) cur[q] = 0;
    __syncthreads();
    int base = bl * CHUNK;
    #pragma unroll 4
    for (int it = 0; it < CHUNK / 256; ++it) {
        int e = base + it * 256 + tid;
        if (e < E) atomicAdd(&cur[dst[e] >> BSHIFT], 1);
    }
    __syncthreads();
    {
        int carry = 0;
        int lane = tid & 63, w = tid >> 6;
        for (int bb = 0; bb < NBKT; bb += 256) {
            int v = (bb + tid < NBKT) ? cur[bb + tid] : 0;
            int inc = wave_scan_incl(v, lane);
            __syncthreads();
            if (lane == 63) wpart[w] = inc;
            __syncthreads();
            int woff = 0;
            #pragma unroll
            for (int k = 0; k < 4; ++k) if (k < w) woff += wpart[k];
            int tot = wpart[0] + wpart[1] + wpart[2] + wpart[3];
            if (bb + tid < NBKT) off[bb + tid] = carry + woff + inc - v;
            carry += tot;
        }
        if (tid == 0) off[NBKT] = carry;
    }
    __syncthreads();
    for (int q = tid; q < NBKT; q += 256) {
        cur[q] = off[q];
        gb2[q] = blkoff[coff + bl * NBKT + q] - off[q];
    }
    __syncthreads();
    #pragma unroll 4
    for (int it = 0; it < CHUNK / 256; ++it) {
        int e = base + it * 256 + tid;
        if (e < E) {
            int d = dst[e];
            int q = d >> BSHIFT;
            int s = atomicAdd(&cur[q], 1);
            lpk[s] = src[e] | ((d & BMASK) << 17);
            lga[s] = gb2[q] + s;
        }
    }
    __syncthreads();
    int cnt_tot = min(CHUNK, E - base);
    for (int s = tid; s < cnt_tot; s += 256)
        pairs[lga[s]] = lpk[s];
}

// per-bucket counting sort: pairs -> node-ordered src lists (in place) + noff[N+1].
// Level-0 blocks also emit xs = bf16(dinv0*x).
__global__ __launch_bounds__(256) void sort_pass(
    int* __restrict__ pairs0, int* __restrict__ pairs1,
    const int* __restrict__ bktbase,
    int* __restrict__ noff0, int* __restrict__ noff1,
    const float* __restrict__ x, ushort* __restrict__ xs)
{
    __shared__ int lpk[SRCCAP];
    __shared__ int cnt[64];
    __shared__ int cur[64];
    __shared__ float dvl[64];
    int qg = blockIdx.x;
    int* pairs; int* noff; int q, boff, N, nbkt;
    bool lvl0 = qg < NBKT0;
    if (lvl0) { pairs = pairs0; noff = noff0; q = qg; boff = 0; N = N0; nbkt = NBKT0; }
    else { pairs = pairs1; noff = noff1; q = qg - NBKT0; boff = NBKT0 + 1; N = N1; nbkt = NBKT1; }
    int tid = threadIdx.x;
    if (tid < 64) cnt[tid] = 0;
    __syncthreads();
    int s0 = bktbase[boff + q], s1 = bktbase[boff + q + 1];
    int m = min(s1 - s0, SRCCAP);
    for (int s = tid; s < m; s += 256) {
        int pk = pairs[s0 + s];
        lpk[s] = pk;
        atomicAdd(&cnt[(pk >> 17) & BMASK], 1);
    }
    __syncthreads();
    if (tid < 64) {
        int v = cnt[tid];
        int inc = wave_scan_incl(v, tid);
        cur[tid] = inc - v;
        dvl[tid] = rsqrtf((float)v + 2.0f);
        int i = q * 64 + tid;
        if (i < N) noff[i] = s0 + inc - v;
        if (q == nbkt - 1 && tid == 0) noff[N] = s1;
    }
    __syncthreads();
    for (int s = tid; s < m; s += 256) {
        int pk = lpk[s];
        int p = atomicAdd(&cur[(pk >> 17) & BMASK], 1);
        pairs[s0 + p] = pk & 0x1FFFF;
    }
    if (lvl0) {
        for (int idx = tid; idx < 64 * 64; idx += 256) {
            int nl = idx >> 6, col = idx & 63;
            size_t i = (size_t)q * 64 + nl;          // N0 == 1250*64
            xs[i * CIN + col] = f2bf(dvl[nl] * x[i * CIN + col]);
        }
    }
}

// ---------------------------------------------------------------------------
// Fused L0: agg(xs, ei0) -> gemm0(W0,+b,relu) -> gemm1(W1, *dinv1) -> T[0:N1]
// grid = N1/64 blocks (h0 rows >= N1 are discarded by the reference pooling).
__global__ __launch_bounds__(256) void fused_l0(
    const int* __restrict__ noff0, const int* __restrict__ csr0,
    const ushort* __restrict__ xs,
    const ushort* __restrict__ Wt0, const float* __restrict__ b0,
    const ushort* __restrict__ Wt1, const int* __restrict__ noff1,
    ushort* __restrict__ Tout)
{
    __shared__ ushort al[64 * 64];    // agg tile (K=64), swizzled 16B groups
    __shared__ ushort hl[64 * 128];   // h0 tile (K=128), swizzled 16B groups
    const int tid = threadIdx.x;
    const int rowbase = blockIdx.x * 64;

    // ---- gather phase (16 lanes per node, 4 cols each) ----
    {
        const int grp = tid >> 4, ln = tid & 15;
        for (int dd = grp; dd < 64; dd += 16) {
            int i = rowbase + dd;
            short4v o = {0, 0, 0, 0};
            if (i < N1) {
                int e = noff0[i], e1 = noff0[i + 1];
                float dv = rsqrtf((float)(e1 - e) + 2.f);
                float acc[4] = {0.f, 0.f, 0.f, 0.f};
                for (; e + 4 <= e1; e += 4) {
                    int sa = csr0[e], sb = csr0[e + 1], sc = csr0[e + 2], sd = csr0[e + 3];
                    short4v va = *reinterpret_cast<const short4v*>(xs + (size_t)sa * CIN + ln * 4);
                    short4v vb = *reinterpret_cast<const short4v*>(xs + (size_t)sb * CIN + ln * 4);
                    short4v vc = *reinterpret_cast<const short4v*>(xs + (size_t)sc * CIN + ln * 4);
                    short4v vd = *reinterpret_cast<const short4v*>(xs + (size_t)sd * CIN + ln * 4);
                    #pragma unroll
                    for (int j = 0; j < 4; ++j)
                        acc[j] += (bf2f((ushort)va[j]) + bf2f((ushort)vb[j]))
                                + (bf2f((ushort)vc[j]) + bf2f((ushort)vd[j]));
                }
                for (; e < e1; ++e) {
                    int s = csr0[e];
                    short4v v = *reinterpret_cast<const short4v*>(xs + (size_t)s * CIN + ln * 4);
                    #pragma unroll
                    for (int j = 0; j < 4; ++j) acc[j] += bf2f((ushort)v[j]);
                }
                short4v t4 = *reinterpret_cast<const short4v*>(xs + (size_t)i * CIN + ln * 4);
                #pragma unroll
                for (int j = 0; j < 4; ++j)
                    o[j] = (short)f2bf(dv * (acc[j] + 2.f * bf2f((ushort)t4[j])));
            }
            int g = ln >> 1, sub = ln & 1;
            *reinterpret_cast<short4v*>(
                &al[dd * 64 + (((g ^ (dd & 7)) << 3) | (sub << 2))]) = o;
        }
    }
    __syncthreads();

    const int wid = tid >> 6, lane = tid & 63, l15 = lane & 15, lhi = lane >> 4;
    const int arow = wid * 16 + l15;

    // ---- gemm0: h0 = relu(agg @ W0 + b0) -> hl ----
    {
        short8 a0[2];
        #pragma unroll
        for (int kb = 0; kb < 2; ++kb) {
            int g = kb * 4 + lhi;
            a0[kb] = *reinterpret_cast<const short8*>(&al[arow * 64 + ((g ^ (arow & 7)) << 3)]);
        }
        f32x4 c0[8];
        #pragma unroll
        for (int nf = 0; nf < 8; ++nf) c0[nf] = f32x4{0.f, 0.f, 0.f, 0.f};
        #pragma unroll
        for (int nf = 0; nf < 8; ++nf) {
            #pragma unroll
            for (int kb = 0; kb < 2; ++kb) {
                short8 b = *reinterpret_cast<const short8*>(
                    &Wt0[(size_t)(nf * 16 + l15) * CIN + kb * 32 + lhi * 8]);
                c0[nf] = __builtin_amdgcn_mfma_f32_16x16x32_bf16(a0[kb], b, c0[nf], 0, 0, 0);
            }
        }
        #pragma unroll
        for (int j = 0; j < 4; ++j) {
            int mrow = wid * 16 + lhi * 4 + j;
            #pragma unroll
            for (int nf = 0; nf < 8; ++nf) {
                int n = nf * 16 + l15;
                float v = fmaxf(c0[nf][j] + b0[n], 0.f);
                int g = n >> 3, sub = n & 7;
                hl[mrow * 128 + (((g ^ (mrow & 15)) << 3) | sub)] = f2bf(v);
            }
        }
    }
    __syncthreads();

    // ---- gemm1: T = dinv1 * (h0 @ W1) ----
    short8 a1[4];
    #pragma unroll
    for (int kb = 0; kb < 4; ++kb) {
        int g = kb * 4 + lhi;
        a1[kb] = *reinterpret_cast<const short8*>(&hl[arow * 128 + ((g ^ (arow & 15)) << 3)]);
    }
    f32x4 c1[8];
    #pragma unroll
    for (int nf = 0; nf < 8; ++nf) c1[nf] = f32x4{0.f, 0.f, 0.f, 0.f};
    #pragma unroll
    for (int nf = 0; nf < 8; ++nf) {
        #pragma unroll
        for (int kb = 0; kb < 4; ++kb) {
            short8 b = *reinterpret_cast<const short8*>(
                &Wt1[(size_t)(nf * 16 + l15) * HN + kb * 32 + lhi * 8]);
            c1[nf] = __builtin_amdgcn_mfma_f32_16x16x32_bf16(a1[kb], b, c1[nf], 0, 0, 0);
        }
    }
    #pragma unroll
    for (int j = 0; j < 4; ++j) {
        int m = rowbase + wid * 16 + lhi * 4 + j;
        if (m >= N1) continue;
        float d = rsqrtf((float)(noff1[m + 1] - noff1[m]) + 2.f);
        #pragma unroll
        for (int nf = 0; nf < 8; ++nf) {
            int n = nf * 16 + l15;
            Tout[(size_t)m * HN + n] = f2bf(c1[nf][j] * d);
        }
    }
}

// ---------------------------------------------------------------------------
// Fused gather+GEMM (K=128): h = relu?(dv*(agg T + 2T) + gbias) per row (<NG, else 0),
// then out = [h @ Wt (+ev*Wex) (+gemmbias)] (*dinv via snoff)
template<bool GBIAS, bool EXTRA, bool GEMMBIAS, bool SCALE, bool OUTF32>
__global__ __launch_bounds__(256) void fused_gg(
    const int* __restrict__ noff, const int* __restrict__ csr,
    const ushort* __restrict__ T,
    const float* __restrict__ gbias, int NG,
    const float* __restrict__ extraVal, int extraLimit, const float* __restrict__ Wex,
    const ushort* __restrict__ Wt, const float* __restrict__ gemmbias,
    const int* __restrict__ snoff,
    void* __restrict__ dstv, int M)
{
    __shared__ ushort hl[64 * 128];
    const int tid = threadIdx.x;
    const int rowbase = blockIdx.x * 64;

    // ---- gather phase (16 lanes per node, 8 cols each) ----
    {
        const int grp = tid >> 4, ln = tid & 15;
        for (int dd = grp; dd < 64; dd += 16) {
            int i = rowbase + dd;
            short8 o = {0, 0, 0, 0, 0, 0, 0, 0};
            if (i < NG) {
                int e = noff[i], e1 = noff[i + 1];
                float dv = rsqrtf((float)(e1 - e) + 2.f);
                float acc[8] = {0.f, 0.f, 0.f, 0.f, 0.f, 0.f, 0.f, 0.f};
                for (; e + 4 <= e1; e += 4) {
                    int sa = csr[e], sb = csr[e + 1], sc = csr[e + 2], sd = csr[e + 3];
                    short8 va = *reinterpret_cast<const short8*>(T + (size_t)sa * HN + ln * 8);
                    short8 vb = *reinterpret_cast<const short8*>(T + (size_t)sb * HN + ln * 8);
                    short8 vc = *reinterpret_cast<const short8*>(T + (size_t)sc * HN + ln * 8);
                    short8 vd = *reinterpret_cast<const short8*>(T + (size_t)sd * HN + ln * 8);
                    #pragma unroll
                    for (int j = 0; j < 8; ++j)
                        acc[j] += (bf2f((ushort)va[j]) + bf2f((ushort)vb[j]))
                                + (bf2f((ushort)vc[j]) + bf2f((ushort)vd[j]));
                }
                for (; e < e1; ++e) {
                    int s = csr[e];
                    short8 v = *reinterpret_cast<const short8*>(T + (size_t)s * HN + ln * 8);
                    #pragma unroll
                    for (int j = 0; j < 8; ++j) acc[j] += bf2f((ushort)v[j]);
                }
                short8 t8 = *reinterpret_cast<const short8*>(T + (size_t)i * HN + ln * 8);
                #pragma unroll
                for (int j = 0; j < 8; ++j) {
                    float v = dv * (acc[j] + 2.f * bf2f((ushort)t8[j]));
                    if (GBIAS) v = fmaxf(v + gbias[ln * 8 + j], 0.f);
                    o[j] = (short)f2bf(v);
                }
            }
            *reinterpret_cast<short8*>(&hl[dd * 128 + ((ln ^ (dd & 15)) << 3)]) = o;
        }
    }
    __syncthreads();

    // ---- GEMM phase ----
    const int wid = tid >> 6, lane = tid & 63, l15 = lane & 15, lhi = lane >> 4;
    const int arow = wid * 16 + l15;
    short8 a[4];
    #pragma unroll
    for (int kb = 0; kb < 4; ++kb) {
        int g = kb * 4 + lhi;
        a[kb] = *reinterpret_cast<const short8*>(&hl[arow * 128 + ((g ^ (arow & 15)) << 3)]);
    }
    f32x4 acc[8];
    #pragma unroll
    for (int nf = 0; nf < 8; ++nf) acc[nf] = f32x4{0.f, 0.f, 0.f, 0.f};
    #pragma unroll
    for (int nf = 0; nf < 8; ++nf) {
        #pragma unroll
        for (int kb = 0; kb < 4; ++kb) {
            short8 b = *reinterpret_cast<const short8*>(
                &Wt[(size_t)(nf * 16 + l15) * HN + kb * 32 + lhi * 8]);
            acc[nf] = __builtin_amdgcn_mfma_f32_16x16x32_bf16(a[kb], b, acc[nf], 0, 0, 0);
        }
    }
    #pragma unroll
    for (int j = 0; j < 4; ++j) {
        int m = rowbase + wid * 16 + lhi * 4 + j;
        if (m >= M) continue;
        float ev = 0.f, d = 1.f;
        if (EXTRA) ev = (m < extraLimit) ? extraVal[m] : 0.f;
        if (SCALE) d = rsqrtf((float)(snoff[m + 1] - snoff[m]) + 2.f);
        #pragma unroll
        for (int nf = 0; nf < 8; ++nf) {
            int n = nf * 16 + l15;
            float v = acc[nf][j];
            if (EXTRA)    v += ev * Wex[n];
            if (GEMMBIAS) v += gemmbias[n];
            if (SCALE)    v *= d;
            if (OUTF32) ((float*)dstv)[(size_t)m * HN + n] = v;
            else        ((ushort*)dstv)[(size_t)m * HN + n] = f2bf(v);
        }
    }
}

inline int cdiv(int a, int b) { return (a + b - 1) / b; }

} // namespace

extern "C" void kernel_launch(void* const* d_in, const int* in_sizes, int n_in,
                              void* d_out, int out_size, void* d_ws, size_t ws_size,
                              hipStream_t stream)
{
    const float* x       = (const float*)d_in[0];
    const float* W_down0 = (const float*)d_in[2];
    const float* b_down0 = (const float*)d_in[3];
    const float* W_down1 = (const float*)d_in[4];
    const float* b_down1 = (const float*)d_in[5];
    const float* W_up0   = (const float*)d_in[6];
    const float* b_up0   = (const float*)d_in[7];
    const float* W_up1   = (const float*)d_in[8];
    const float* b_up1   = (const float*)d_in[9];
    const float* W_lin   = (const float*)d_in[10];
    const float* b_lin   = (const float*)d_in[11];
    const int*   ei0     = (const int*)d_in[12];
    const int*   ei1     = (const int*)d_in[13];
    const int*   ei2     = (const int*)d_in[14];

    char* ws = (char*)d_ws;
    size_t o = 0;
    auto carve = [&](size_t bytes) { void* p = ws + o; o += (bytes + 15) & ~size_t(15); return p; };

    ushort* X     = (ushort*)carve((size_t)N0 * HN * 2);   // also hosts xs during setup/L0
    ushort* T     = (ushort*)carve((size_t)N0 * HN * 2);
    ushort* Wt0   = (ushort*)carve((size_t)HN * CIN * 2);
    ushort* Wt1   = (ushort*)carve((size_t)HN * HN * 2);
    ushort* Wt2   = (ushort*)carve((size_t)HN * HN * 2);
    ushort* Wt3   = (ushort*)carve((size_t)HN * HN * 2);
    ushort* Wt4   = (ushort*)carve((size_t)HN * HN * 2);
    int*    pairs0 = (int*)carve((size_t)E0 * 4);
    int*    pairs1 = (int*)carve((size_t)E1 * 4);
    int*    blkcnt = (int*)carve((size_t)(NBLK0 * NBKT0 + NBLK1 * NBKT1) * 4);
    int*    blkoff = (int*)carve((size_t)(NBLK0 * NBKT0 + NBLK1 * NBKT1) * 4);
    int*    bktbase = (int*)carve((size_t)(NBKT0 + NBKT1 + 2) * 4);
    int*    noff0 = (int*)carve((size_t)(N0 + 1) * 4);
    int*    noff1 = (int*)carve((size_t)(N1 + 1) * 4);
    // contiguous zero block
    size_t zero_off = o;
    int*    bkttot = (int*)carve((size_t)(NBKT0 + NBKT1) * 4);
    float*  cntE   = (float*)carve((size_t)N2 * 4);
    size_t zero_bytes = o - zero_off;

    ushort* xs = X;   // xs [N0 x 64] bf16 lives in X until F2 overwrites it

    hipMemsetAsync(ws + zero_off, 0, zero_bytes, stream);

    // ---- setup ----
    setup_small<<<dim3(cdiv(2 * E2, 256), 2), 256, 0, stream>>>(
        ei2, cntE, W_down0, W_down1, W_up0, W_up1, W_lin, Wt0, Wt1, Wt2, Wt3, Wt4);
    count_pass<<<NBLK0 + NBLK1, 256, 0, stream>>>(ei0, ei1, blkcnt, bkttot);
    scanB<<<2, 64, 0, stream>>>(bkttot, bktbase);
    scanC<<<NBKT0 + NBKT1, 64, 0, stream>>>(blkcnt, bktbase, blkoff);
    partition_pass<<<NBLK0 + NBLK1, 256, 0, stream>>>(ei0, ei1, blkoff, pairs0, pairs1);
    sort_pass<<<NBKT0 + NBKT1, 256, 0, stream>>>(pairs0, pairs1, bktbase,
                                                 noff0, noff1, x, xs);

    const int* bktbase1 = bktbase + NBKT0 + 1;
    (void)bktbase1;

    // ---- F01: xs --agg0--> gemm0(relu) --> gemm1(*dinv1) --> T[0:N1] ----
    fused_l0<<<cdiv(N1, 64), 256, 0, stream>>>(
        noff0, pairs0, xs, Wt0, b_down0, Wt1, noff1, T);

    // ---- F2: T --agg1(relu,b_down1; rows<N2)--> gemm(W_up0 + cntE*Wex, *dinv1) --> X[0:N1] ----
    fused_gg<true, true, false, true, false><<<cdiv(N1, 64), 256, 0, stream>>>(
        noff1, pairs1, T, b_down1, N2,
        cntE, N2, W_up0 + 128 * HN, Wt2, nullptr, noff1, X, N1);

    // ---- F3: X --agg1(relu,b_up0; rows<N1)--> gemm(W_up1 + cntE*Wex, *dinv0) --> T[0:N0] ----
    fused_gg<true, true, false, true, false><<<cdiv(N0, 64), 256, 0, stream>>>(
        noff1, pairs1, X, b_up0, N1,
        cntE, N2, W_up1 + 128 * HN, Wt3, nullptr, noff0, T, N0);

    // ---- F4: T --agg0(relu,b_up1)--> gemm(W_lin + b_lin) --> d_out (f32) ----
    fused_gg<true, false, true, false, true><<<cdiv(N0, 64), 256, 0, stream>>>(
        noff0, pairs0, T, b_up1, N0,
        nullptr, 0, nullptr, Wt4, b_lin, nullptr, d_out, N0);
}

// Round 8
// 286.344 us; speedup vs baseline: 20.9612x; 1.0601x over previous
//
#include <hip/hip_runtime.h>
#include <hip/hip_bf16.h>

namespace {

constexpr int HN  = 128;
constexpr int N0  = 80000, N1 = 60000, N2 = 45000;
constexpr int CIN = 64;
constexpr int E0  = 1280000, E1 = 360000, E2 = 315000;

constexpr int BSHIFT = 6;                 // 64 dst nodes per bucket
constexpr int BMASK  = 63;
constexpr int NBKT0  = (N0 + 63) / 64;    // 1250
constexpr int NBKT1  = (N1 + 63) / 64;    // 938
constexpr int CHUNK  = 8192;              // edges per partition block
constexpr int NBLK0  = (E0 + CHUNK - 1) / CHUNK;  // 157
constexpr int NBLK1  = (E1 + CHUNK - 1) / CHUNK;  // 44
constexpr int SRCCAP = 2560;              // LDS staging per bucket

using short8  = __attribute__((ext_vector_type(8))) short;
using short4v = __attribute__((ext_vector_type(4))) short;
using f32x4   = __attribute__((ext_vector_type(4))) float;

__device__ inline ushort f2bf(float f) {
    uint u = __float_as_uint(f);
    u += 0x7fffu + ((u >> 16) & 1u);
    return (ushort)(u >> 16);
}
__device__ inline float bf2f(ushort u) {
    return __uint_as_float(((uint)u) << 16);
}

__device__ inline int wave_scan_incl(int v, int lane) {
    #pragma unroll
    for (int d = 1; d < 64; d <<= 1) {
        int t = __shfl_up(v, d, 64);
        if (lane >= d) v += t;
    }
    return v;
}

// y=0: E2 histogram (fire-and-forget float atomics; integer-exact); y=1: weight transpose->bf16
__global__ __launch_bounds__(256) void setup_small(
    const int* __restrict__ ei2, float* __restrict__ cntE,
    const float* __restrict__ W0, const float* __restrict__ W1,
    const float* __restrict__ W2, const float* __restrict__ W3,
    const float* __restrict__ W4,
    ushort* __restrict__ T0, ushort* __restrict__ T1, ushort* __restrict__ T2,
    ushort* __restrict__ T3, ushort* __restrict__ T4)
{
    int idx = blockIdx.x * 256 + threadIdx.x;
    if (blockIdx.y == 0) {
        if (idx < 2 * E2) unsafeAtomicAdd(&cntE[ei2[idx]], 1.0f);
    } else {
        if (idx >= CIN * HN + 4 * HN * HN) return;
        const float* W; ushort* T; int K, local;
        if (idx < CIN * HN) { W = W0; T = T0; K = CIN; local = idx; }
        else {
            int r = idx - CIN * HN;
            int m = r >> 14; local = r & 16383; K = HN;
            switch (m) { case 0: W = W1; T = T1; break; case 1: W = W2; T = T2; break;
                         case 2: W = W3; T = T3; break; default: W = W4; T = T4; break; }
        }
        int n = local / K, k = local - n * K;
        T[local] = f2bf(W[k * HN + n]);
    }
}

// per-(block,bucket) counts + bucket totals
__global__ __launch_bounds__(512) void count_pass(
    const int* __restrict__ ei0, const int* __restrict__ ei1,
    int* __restrict__ blkcnt, int* __restrict__ bkttot)
{
    __shared__ int cnt[NBKT0];
    int b = blockIdx.x;
    const int* dst; int E, NBKT, bl, coff, toff;
    if (b < NBLK0) { dst = ei0 + E0; E = E0; NBKT = NBKT0; bl = b; coff = 0; toff = 0; }
    else { dst = ei1 + E1; E = E1; NBKT = NBKT1; bl = b - NBLK0; coff = NBLK0 * NBKT0; toff = NBKT0; }
    int tid = threadIdx.x;
    for (int q = tid; q < NBKT; q += 512) cnt[q] = 0;
    __syncthreads();
    int base = bl * CHUNK;
    #pragma unroll 4
    for (int it = 0; it < CHUNK / 512; ++it) {
        int e = base + it * 512 + tid;
        if (e < E) atomicAdd(&cnt[dst[e] >> BSHIFT], 1);
    }
    __syncthreads();
    for (int q = tid; q < NBKT; q += 512) {
        int c = cnt[q];
        blkcnt[coff + bl * NBKT + q] = c;
        if (c) atomicAdd(&bkttot[toff + q], c);
    }
}

// exclusive scan of bucket totals per level (+ sentinel)
__global__ void scanB(const int* __restrict__ bkttot, int* __restrict__ bktbase) {
    int seg = blockIdx.x;
    int n = seg ? NBKT1 : NBKT0;
    const int* src = bkttot + (seg ? NBKT0 : 0);
    int* dst = bktbase + (seg ? NBKT0 + 1 : 0);
    int lane = threadIdx.x;
    int carry = 0;
    for (int base = 0; base < n; base += 64) {
        int v = (base + lane < n) ? src[base + lane] : 0;
        int inc = wave_scan_incl(v, lane);
        if (base + lane < n) dst[base + lane] = carry + inc - v;
        carry += __shfl(inc, 63, 64);
    }
    if (lane == 0) dst[n] = carry;
}

// per-bucket scan over blocks -> absolute output cursor per (block,bucket)
__global__ void scanC(const int* __restrict__ blkcnt, const int* __restrict__ bktbase,
                      int* __restrict__ blkoff)
{
    int qg = blockIdx.x;
    int NBKT, NBLK, coff, q, boff;
    if (qg < NBKT0) { NBKT = NBKT0; NBLK = NBLK0; coff = 0; q = qg; boff = 0; }
    else { NBKT = NBKT1; NBLK = NBLK1; coff = NBLK0 * NBKT0; q = qg - NBKT0; boff = NBKT0 + 1; }
    int lane = threadIdx.x;
    int basev = bktbase[boff + q];
    int carry = 0;
    for (int base = 0; base < NBLK; base += 64) {
        int b = base + lane;
        int v = (b < NBLK) ? blkcnt[coff + b * NBKT + q] : 0;
        int inc = wave_scan_incl(v, lane);
        if (b < NBLK) blkoff[coff + b * NBKT + q] = basev + carry + inc - v;
        carry += __shfl(inc, 63, 64);
    }
}

// LDS-staged radix partition: pairs[slot] = src | (dst&63)<<17, grouped by dst>>6
__global__ __launch_bounds__(512) void partition_pass(
    const int* __restrict__ ei0, const int* __restrict__ ei1,
    const int* __restrict__ blkoff,
    int* __restrict__ pairs0, int* __restrict__ pairs1)
{
    __shared__ int off[NBKT0 + 1];
    __shared__ int cur[NBKT0];
    __shared__ int gb2[NBKT0];
    __shared__ int lpk[CHUNK];
    __shared__ int lga[CHUNK];
    __shared__ int wpart[8];
    int b = blockIdx.x;
    const int* src; const int* dst; int* pairs; int E, NBKT, bl, coff;
    if (b < NBLK0) { src = ei0; dst = ei0 + E0; pairs = pairs0; E = E0; NBKT = NBKT0; bl = b; coff = 0; }
    else { src = ei1; dst = ei1 + E1; pairs = pairs1; E = E1; NBKT = NBKT1; bl = b - NBLK0; coff = NBLK0 * NBKT0; }
    int tid = threadIdx.x;
    for (int q = tid; q < NBKT; q += 512) cur[q] = 0;
    __syncthreads();
    int base = bl * CHUNK;
    #pragma unroll 4
    for (int it = 0; it < CHUNK / 512; ++it) {
        int e = base + it * 512 + tid;
        if (e < E) atomicAdd(&cur[dst[e] >> BSHIFT], 1);
    }
    __syncthreads();
    {
        int carry = 0;
        int lane = tid & 63, w = tid >> 6;
        for (int bb = 0; bb < NBKT; bb += 512) {
            int v = (bb + tid < NBKT) ? cur[bb + tid] : 0;
            int inc = wave_scan_incl(v, lane);
            __syncthreads();
            if (lane == 63) wpart[w] = inc;
            __syncthreads();
            int woff = 0, tot = 0;
            #pragma unroll
            for (int k = 0; k < 8; ++k) { if (k < w) woff += wpart[k]; tot += wpart[k]; }
            if (bb + tid < NBKT) off[bb + tid] = carry + woff + inc - v;
            carry += tot;
        }
        if (tid == 0) off[NBKT] = carry;
    }
    __syncthreads();
    for (int q = tid; q < NBKT; q += 512) {
        cur[q] = off[q];
        gb2[q] = blkoff[coff + bl * NBKT + q] - off[q];
    }
    __syncthreads();
    #pragma unroll 4
    for (int it = 0; it < CHUNK / 512; ++it) {
        int e = base + it * 512 + tid;
        if (e < E) {
            int d = dst[e];
            int q = d >> BSHIFT;
            int s = atomicAdd(&cur[q], 1);
            lpk[s] = src[e] | ((d & BMASK) << 17);
            lga[s] = gb2[q] + s;
        }
    }
    __syncthreads();
    int cnt_tot = min(CHUNK, E - base);
    for (int s = tid; s < cnt_tot; s += 512)
        pairs[lga[s]] = lpk[s];
}

// per-bucket counting sort: pairs -> node-ordered src lists (in place) + noff[N+1].
// Level-0 blocks also emit xs = bf16(dinv0*x).
__global__ __launch_bounds__(256) void sort_pass(
    int* __restrict__ pairs0, int* __restrict__ pairs1,
    const int* __restrict__ bktbase,
    int* __restrict__ noff0, int* __restrict__ noff1,
    const float* __restrict__ x, ushort* __restrict__ xs)
{
    __shared__ int lpk[SRCCAP];
    __shared__ int cnt[64];
    __shared__ int cur[64];
    __shared__ float dvl[64];
    int qg = blockIdx.x;
    int* pairs; int* noff; int q, boff, N, nbkt;
    bool lvl0 = qg < NBKT0;
    if (lvl0) { pairs = pairs0; noff = noff0; q = qg; boff = 0; N = N0; nbkt = NBKT0; }
    else { pairs = pairs1; noff = noff1; q = qg - NBKT0; boff = NBKT0 + 1; N = N1; nbkt = NBKT1; }
    int tid = threadIdx.x;
    if (tid < 64) cnt[tid] = 0;
    __syncthreads();
    int s0 = bktbase[boff + q], s1 = bktbase[boff + q + 1];
    int m = min(s1 - s0, SRCCAP);
    for (int s = tid; s < m; s += 256) {
        int pk = pairs[s0 + s];
        lpk[s] = pk;
        atomicAdd(&cnt[(pk >> 17) & BMASK], 1);
    }
    __syncthreads();
    if (tid < 64) {
        int v = cnt[tid];
        int inc = wave_scan_incl(v, tid);
        cur[tid] = inc - v;
        dvl[tid] = rsqrtf((float)v + 2.0f);
        int i = q * 64 + tid;
        if (i < N) noff[i] = s0 + inc - v;
        if (q == nbkt - 1 && tid == 0) noff[N] = s1;
    }
    __syncthreads();
    for (int s = tid; s < m; s += 256) {
        int pk = lpk[s];
        int p = atomicAdd(&cur[(pk >> 17) & BMASK], 1);
        pairs[s0 + p] = pk & 0x1FFFF;
    }
    if (lvl0) {
        for (int idx = tid; idx < 64 * 64; idx += 256) {
            int nl = idx >> 6, col = idx & 63;
            size_t i = (size_t)q * 64 + nl;          // N0 == 1250*64
            xs[i * CIN + col] = f2bf(dvl[nl] * x[i * CIN + col]);
        }
    }
}

// ---------------------------------------------------------------------------
// Fused L0 (512 thr): agg(xs, ei0) -> gemm0(W0,+b,relu) -> gemm1(W1,*dinv1) -> T[0:N1]
__global__ __launch_bounds__(512) void fused_l0(
    const int* __restrict__ noff0, const int* __restrict__ csr0,
    const ushort* __restrict__ xs,
    const ushort* __restrict__ Wt0, const float* __restrict__ b0,
    const ushort* __restrict__ Wt1, const int* __restrict__ noff1,
    ushort* __restrict__ Tout)
{
    __shared__ ushort al[64 * 64];    // agg tile (K=64), swizzled 16B groups
    __shared__ ushort hl[64 * 128];   // h0 tile (K=128), swizzled 16B groups
    const int tid = threadIdx.x;
    const int rowbase = blockIdx.x * 64;

    // ---- gather phase: 32 groups x 16 lanes, 2 rows per group ----
    {
        const int grp = tid >> 4, ln = tid & 15;
        #pragma unroll
        for (int half = 0; half < 2; ++half) {
            int dd = grp + half * 32;
            int i = rowbase + dd;
            short4v o = {0, 0, 0, 0};
            if (i < N1) {
                int e = noff0[i], e1 = noff0[i + 1];
                float dv = rsqrtf((float)(e1 - e) + 2.f);
                float acc[4] = {0.f, 0.f, 0.f, 0.f};
                for (; e + 4 <= e1; e += 4) {
                    int sa = csr0[e], sb = csr0[e + 1], sc = csr0[e + 2], sd = csr0[e + 3];
                    short4v va = *reinterpret_cast<const short4v*>(xs + (size_t)sa * CIN + ln * 4);
                    short4v vb = *reinterpret_cast<const short4v*>(xs + (size_t)sb * CIN + ln * 4);
                    short4v vc = *reinterpret_cast<const short4v*>(xs + (size_t)sc * CIN + ln * 4);
                    short4v vd = *reinterpret_cast<const short4v*>(xs + (size_t)sd * CIN + ln * 4);
                    #pragma unroll
                    for (int j = 0; j < 4; ++j)
                        acc[j] += (bf2f((ushort)va[j]) + bf2f((ushort)vb[j]))
                                + (bf2f((ushort)vc[j]) + bf2f((ushort)vd[j]));
                }
                for (; e < e1; ++e) {
                    int s = csr0[e];
                    short4v v = *reinterpret_cast<const short4v*>(xs + (size_t)s * CIN + ln * 4);
                    #pragma unroll
                    for (int j = 0; j < 4; ++j) acc[j] += bf2f((ushort)v[j]);
                }
                short4v t4 = *reinterpret_cast<const short4v*>(xs + (size_t)i * CIN + ln * 4);
                #pragma unroll
                for (int j = 0; j < 4; ++j)
                    o[j] = (short)f2bf(dv * (acc[j] + 2.f * bf2f((ushort)t4[j])));
            }
            int g = ln >> 1, sub = ln & 1;
            *reinterpret_cast<short4v*>(
                &al[dd * 64 + (((g ^ (dd & 7)) << 3) | (sub << 2))]) = o;
        }
    }
    __syncthreads();

    const int wid = tid >> 6, lane = tid & 63, l15 = lane & 15, lhi = lane >> 4;
    const int mq = wid & 3, nh = wid >> 2;
    const int arow = mq * 16 + l15;

    // ---- gemm0: h0 = relu(agg @ W0 + b0) -> hl (each wave: 16 rows x 64 cols) ----
    {
        short8 a0[2];
        #pragma unroll
        for (int kb = 0; kb < 2; ++kb) {
            int g = kb * 4 + lhi;
            a0[kb] = *reinterpret_cast<const short8*>(&al[arow * 64 + ((g ^ (arow & 7)) << 3)]);
        }
        f32x4 c0[4];
        #pragma unroll
        for (int nf = 0; nf < 4; ++nf) c0[nf] = f32x4{0.f, 0.f, 0.f, 0.f};
        #pragma unroll
        for (int nf = 0; nf < 4; ++nf) {
            #pragma unroll
            for (int kb = 0; kb < 2; ++kb) {
                short8 b = *reinterpret_cast<const short8*>(
                    &Wt0[(size_t)((nh * 4 + nf) * 16 + l15) * CIN + kb * 32 + lhi * 8]);
                c0[nf] = __builtin_amdgcn_mfma_f32_16x16x32_bf16(a0[kb], b, c0[nf], 0, 0, 0);
            }
        }
        #pragma unroll
        for (int j = 0; j < 4; ++j) {
            int mrow = mq * 16 + lhi * 4 + j;
            #pragma unroll
            for (int nf = 0; nf < 4; ++nf) {
                int n = (nh * 4 + nf) * 16 + l15;
                float v = fmaxf(c0[nf][j] + b0[n], 0.f);
                int g = n >> 3, sub = n & 7;
                hl[mrow * 128 + (((g ^ (mrow & 15)) << 3) | sub)] = f2bf(v);
            }
        }
    }
    __syncthreads();

    // ---- gemm1: T = dinv1 * (h0 @ W1) ----
    short8 a1[4];
    #pragma unroll
    for (int kb = 0; kb < 4; ++kb) {
        int g = kb * 4 + lhi;
        a1[kb] = *reinterpret_cast<const short8*>(&hl[arow * 128 + ((g ^ (arow & 15)) << 3)]);
    }
    f32x4 c1[4];
    #pragma unroll
    for (int nf = 0; nf < 4; ++nf) c1[nf] = f32x4{0.f, 0.f, 0.f, 0.f};
    #pragma unroll
    for (int nf = 0; nf < 4; ++nf) {
        #pragma unroll
        for (int kb = 0; kb < 4; ++kb) {
            short8 b = *reinterpret_cast<const short8*>(
                &Wt1[(size_t)((nh * 4 + nf) * 16 + l15) * HN + kb * 32 + lhi * 8]);
            c1[nf] = __builtin_amdgcn_mfma_f32_16x16x32_bf16(a1[kb], b, c1[nf], 0, 0, 0);
        }
    }
    #pragma unroll
    for (int j = 0; j < 4; ++j) {
        int m = rowbase + mq * 16 + lhi * 4 + j;
        if (m >= N1) continue;
        float d = rsqrtf((float)(noff1[m + 1] - noff1[m]) + 2.f);
        #pragma unroll
        for (int nf = 0; nf < 4; ++nf) {
            int n = (nh * 4 + nf) * 16 + l15;
            Tout[(size_t)m * HN + n] = f2bf(c1[nf][j] * d);
        }
    }
}

// ---------------------------------------------------------------------------
// Fused gather+GEMM (512 thr, K=128): h = relu?(dv*(agg T + 2T) + gbias) per row (<NG else 0),
// then out = [h @ Wt (+ev*Wex) (+gemmbias)] (*dinv via snoff)
template<bool GBIAS, bool EXTRA, bool GEMMBIAS, bool SCALE, bool OUTF32>
__global__ __launch_bounds__(512) void fused_gg(
    const int* __restrict__ noff, const int* __restrict__ csr,
    const ushort* __restrict__ T,
    const float* __restrict__ gbias, int NG,
    const float* __restrict__ extraVal, int extraLimit, const float* __restrict__ Wex,
    const ushort* __restrict__ Wt, const float* __restrict__ gemmbias,
    const int* __restrict__ snoff,
    void* __restrict__ dstv, int M)
{
    __shared__ ushort hl[64 * 128];
    const int tid = threadIdx.x;
    const int rowbase = blockIdx.x * 64;

    // ---- gather phase: 32 groups x 16 lanes, 2 rows per group ----
    {
        const int grp = tid >> 4, ln = tid & 15;
        #pragma unroll
        for (int half = 0; half < 2; ++half) {
            int dd = grp + half * 32;
            int i = rowbase + dd;
            short8 o = {0, 0, 0, 0, 0, 0, 0, 0};
            if (i < NG) {
                int e = noff[i], e1 = noff[i + 1];
                float dv = rsqrtf((float)(e1 - e) + 2.f);
                float acc[8] = {0.f, 0.f, 0.f, 0.f, 0.f, 0.f, 0.f, 0.f};
                for (; e + 4 <= e1; e += 4) {
                    int sa = csr[e], sb = csr[e + 1], sc = csr[e + 2], sd = csr[e + 3];
                    short8 va = *reinterpret_cast<const short8*>(T + (size_t)sa * HN + ln * 8);
                    short8 vb = *reinterpret_cast<const short8*>(T + (size_t)sb * HN + ln * 8);
                    short8 vc = *reinterpret_cast<const short8*>(T + (size_t)sc * HN + ln * 8);
                    short8 vd = *reinterpret_cast<const short8*>(T + (size_t)sd * HN + ln * 8);
                    #pragma unroll
                    for (int j = 0; j < 8; ++j)
                        acc[j] += (bf2f((ushort)va[j]) + bf2f((ushort)vb[j]))
                                + (bf2f((ushort)vc[j]) + bf2f((ushort)vd[j]));
                }
                for (; e < e1; ++e) {
                    int s = csr[e];
                    short8 v = *reinterpret_cast<const short8*>(T + (size_t)s * HN + ln * 8);
                    #pragma unroll
                    for (int j = 0; j < 8; ++j) acc[j] += bf2f((ushort)v[j]);
                }
                short8 t8 = *reinterpret_cast<const short8*>(T + (size_t)i * HN + ln * 8);
                #pragma unroll
                for (int j = 0; j < 8; ++j) {
                    float v = dv * (acc[j] + 2.f * bf2f((ushort)t8[j]));
                    if (GBIAS) v = fmaxf(v + gbias[ln * 8 + j], 0.f);
                    o[j] = (short)f2bf(v);
                }
            }
            *reinterpret_cast<short8*>(&hl[dd * 128 + ((ln ^ (dd & 15)) << 3)]) = o;
        }
    }
    __syncthreads();

    // ---- GEMM phase: 8 waves, each 16 rows x 64 cols ----
    const int wid = tid >> 6, lane = tid & 63, l15 = lane & 15, lhi = lane >> 4;
    const int mq = wid & 3, nh = wid >> 2;
    const int arow = mq * 16 + l15;
    short8 a[4];
    #pragma unroll
    for (int kb = 0; kb < 4; ++kb) {
        int g = kb * 4 + lhi;
        a[kb] = *reinterpret_cast<const short8*>(&hl[arow * 128 + ((g ^ (arow & 15)) << 3)]);
    }
    f32x4 acc[4];
    #pragma unroll
    for (int nf = 0; nf < 4; ++nf) acc[nf] = f32x4{0.f, 0.f, 0.f, 0.f};
    #pragma unroll
    for (int nf = 0; nf < 4; ++nf) {
        #pragma unroll
        for (int kb = 0; kb < 4; ++kb) {
            short8 b = *reinterpret_cast<const short8*>(
                &Wt[(size_t)((nh * 4 + nf) * 16 + l15) * HN + kb * 32 + lhi * 8]);
            acc[nf] = __builtin_amdgcn_mfma_f32_16x16x32_bf16(a[kb], b, acc[nf], 0, 0, 0);
        }
    }
    #pragma unroll
    for (int j = 0; j < 4; ++j) {
        int m = rowbase + mq * 16 + lhi * 4 + j;
        if (m >= M) continue;
        float ev = 0.f, d = 1.f;
        if (EXTRA) ev = (m < extraLimit) ? extraVal[m] : 0.f;
        if (SCALE) d = rsqrtf((float)(snoff[m + 1] - snoff[m]) + 2.f);
        #pragma unroll
        for (int nf = 0; nf < 4; ++nf) {
            int n = (nh * 4 + nf) * 16 + l15;
            float v = acc[nf][j];
            if (EXTRA)    v += ev * Wex[n];
            if (GEMMBIAS) v += gemmbias[n];
            if (SCALE)    v *= d;
            if (OUTF32) ((float*)dstv)[(size_t)m * HN + n] = v;
            else        ((ushort*)dstv)[(size_t)m * HN + n] = f2bf(v);
        }
    }
}

inline int cdiv(int a, int b) { return (a + b - 1) / b; }

} // namespace

extern "C" void kernel_launch(void* const* d_in, const int* in_sizes, int n_in,
                              void* d_out, int out_size, void* d_ws, size_t ws_size,
                              hipStream_t stream)
{
    const float* x       = (const float*)d_in[0];
    const float* W_down0 = (const float*)d_in[2];
    const float* b_down0 = (const float*)d_in[3];
    const float* W_down1 = (const float*)d_in[4];
    const float* b_down1 = (const float*)d_in[5];
    const float* W_up0   = (const float*)d_in[6];
    const float* b_up0   = (const float*)d_in[7];
    const float* W_up1   = (const float*)d_in[8];
    const float* b_up1   = (const float*)d_in[9];
    const float* W_lin   = (const float*)d_in[10];
    const float* b_lin   = (const float*)d_in[11];
    const int*   ei0     = (const int*)d_in[12];
    const int*   ei1     = (const int*)d_in[13];
    const int*   ei2     = (const int*)d_in[14];

    char* ws = (char*)d_ws;
    size_t o = 0;
    auto carve = [&](size_t bytes) { void* p = ws + o; o += (bytes + 15) & ~size_t(15); return p; };

    ushort* X     = (ushort*)carve((size_t)N0 * HN * 2);   // also hosts xs during setup/L0
    ushort* T     = (ushort*)carve((size_t)N0 * HN * 2);
    ushort* Wt0   = (ushort*)carve((size_t)HN * CIN * 2);
    ushort* Wt1   = (ushort*)carve((size_t)HN * HN * 2);
    ushort* Wt2   = (ushort*)carve((size_t)HN * HN * 2);
    ushort* Wt3   = (ushort*)carve((size_t)HN * HN * 2);
    ushort* Wt4   = (ushort*)carve((size_t)HN * HN * 2);
    int*    pairs0 = (int*)carve((size_t)E0 * 4);
    int*    pairs1 = (int*)carve((size_t)E1 * 4);
    int*    blkcnt = (int*)carve((size_t)(NBLK0 * NBKT0 + NBLK1 * NBKT1) * 4);
    int*    blkoff = (int*)carve((size_t)(NBLK0 * NBKT0 + NBLK1 * NBKT1) * 4);
    int*    bktbase = (int*)carve((size_t)(NBKT0 + NBKT1 + 2) * 4);
    int*    noff0 = (int*)carve((size_t)(N0 + 1) * 4);
    int*    noff1 = (int*)carve((size_t)(N1 + 1) * 4);
    // contiguous zero block
    size_t zero_off = o;
    int*    bkttot = (int*)carve((size_t)(NBKT0 + NBKT1) * 4);
    float*  cntE   = (float*)carve((size_t)N2 * 4);
    size_t zero_bytes = o - zero_off;

    ushort* xs = X;   // xs [N0 x 64] bf16 lives in X until F2 overwrites it

    hipMemsetAsync(ws + zero_off, 0, zero_bytes, stream);

    // ---- setup ----
    setup_small<<<dim3(cdiv(2 * E2, 256), 2), 256, 0, stream>>>(
        ei2, cntE, W_down0, W_down1, W_up0, W_up1, W_lin, Wt0, Wt1, Wt2, Wt3, Wt4);
    count_pass<<<NBLK0 + NBLK1, 512, 0, stream>>>(ei0, ei1, blkcnt, bkttot);
    scanB<<<2, 64, 0, stream>>>(bkttot, bktbase);
    scanC<<<NBKT0 + NBKT1, 64, 0, stream>>>(blkcnt, bktbase, blkoff);
    partition_pass<<<NBLK0 + NBLK1, 512, 0, stream>>>(ei0, ei1, blkoff, pairs0, pairs1);
    sort_pass<<<NBKT0 + NBKT1, 256, 0, stream>>>(pairs0, pairs1, bktbase,
                                                 noff0, noff1, x, xs);

    // ---- F01: xs --agg0--> gemm0(relu) --> gemm1(*dinv1) --> T[0:N1] ----
    fused_l0<<<cdiv(N1, 64), 512, 0, stream>>>(
        noff0, pairs0, xs, Wt0, b_down0, Wt1, noff1, T);

    // ---- F2: T --agg1(relu,b_down1; rows<N2)--> gemm(W_up0 + cntE*Wex, *dinv1) --> X[0:N1] ----
    fused_gg<true, true, false, true, false><<<cdiv(N1, 64), 512, 0, stream>>>(
        noff1, pairs1, T, b_down1, N2,
        cntE, N2, W_up0 + 128 * HN, Wt2, nullptr, noff1, X, N1);

    // ---- F3: X --agg1(relu,b_up0; rows<N1)--> gemm(W_up1 + cntE*Wex, *dinv0) --> T[0:N0] ----
    fused_gg<true, true, false, true, false><<<cdiv(N0, 64), 512, 0, stream>>>(
        noff1, pairs1, X, b_up0, N1,
        cntE, N2, W_up1 + 128 * HN, Wt3, nullptr, noff0, T, N0);

    // ---- F4: T --agg0(relu,b_up1)--> gemm(W_lin + b_lin) --> d_out (f32) ----
    fused_gg<true, false, true, false, true><<<cdiv(N0, 64), 512, 0, stream>>>(
        noff0, pairs0, T, b_up1, N0,
        nullptr, 0, nullptr, Wt4, b_lin, nullptr, d_out, N0);
}